// Round 2
// baseline (68432.465 us; speedup 1.0000x reference)
//
#include <hip/hip_runtime.h>
#include <hip/hip_bf16.h>

namespace {
constexpr int B  = 64;
constexpr int T  = 2048;
constexpr int L  = 200;
constexpr int H  = 256;
constexpr int KV = 256;
constexpr int E  = 256;
constexpr int V  = 33;
constexpr int MH = 512;
constexpr int G  = 4 * H;
constexpr int HB = H * B;       // 16384
constexpr int KVB = KV * B;     // 16384
constexpr int CS = 50;          // head chunk (steps)

// ---- legacy (round-0) float layout ----
constexpr long OFF_H   = 0;                        // legacy h dbuf; newpath reuses [0..63] as barrier
constexpr long OFF_C   = OFF_H  + 2L * 3 * HB;
constexpr long OFF_CTX = OFF_C  + 3L * HB;         // ctx double buffer [2][KV][B]
constexpr long OFF_Z   = OFF_CTX + 2L * KV * B;
constexpr long OFF_M   = OFF_Z  + 2L * B;
constexpr long OFF_E   = OFF_M  + B;
constexpr long OFF_HID = OFF_E  + (long)B * T;
constexpr long OFF_XE  = OFF_HID + (long)MH * B;   // xembT [L][E][B] (both paths)
constexpr long FLOATS_OLD = OFF_XE + (long)L * E * B;
constexpr long FLOATBYTES = FLOATS_OLD * 4;
constexpr long KVELEMS = (long)B * T * KV;         // 33,554,432
constexpr long NEED_BF = FLOATBYTES + 2 * KVELEMS * 2;   // legacy + bf16 KV

// ---- new-path extra region (after bf16 KV) ----
constexpr long NOFF      = NEED_BF / 4;            // float offset (16B aligned)
constexpr long NOFF_H01  = NOFF;                   // [2][2][H][B] layers 0,1 ping-pong
constexpr long NOFF_C    = NOFF_H01 + 4L * HB;     // [3][H][B]
constexpr long NOFF_H2   = NOFF_C   + 3L * HB;     // [L+1][H][B]
constexpr long NOFF_CTXA = NOFF_H2  + (long)(L + 1) * HB;   // [L+1][KV][B]
constexpr long NOFF_ZA   = NOFF_CTXA + (long)(L + 1) * KVB; // [L+1][B]
constexpr long NOFF_HIDC = NOFF_ZA  + (long)(L + 1) * B;    // [CS][MH][B]
constexpr long FLOATS_NEW = NOFF_HIDC + (long)CS * MH * B;
constexpr long NEED_NEW   = FLOATS_NEW * 4;        // ~182.1 MB
}

__device__ __forceinline__ float sigm(float x) { return 1.f / (1.f + __expf(-x)); }
__device__ __forceinline__ float tanh_f(float x) {
  float xc = fminf(fmaxf(x, -15.f), 15.f);
  float e2 = __expf(2.f * xc);
  return (e2 - 1.f) / (e2 + 1.f);
}
__device__ __forceinline__ ushort f2bf(float x) {
  unsigned u = __float_as_uint(x);
  unsigned r = (u + 0x7fffu + ((u >> 16) & 1u)) >> 16;
  return (ushort)r;
}
__device__ __forceinline__ float bf2f(unsigned v) { return __uint_as_float(v << 16); }

__device__ __forceinline__ void atomicMaxFloat(float* p, float v) {
  int old = __float_as_int(*p);
  while (__int_as_float(old) < v) {
    int assumed = old;
    old = atomicCAS((int*)p, assumed, __float_as_int(v));
    if (old == assumed) break;
  }
}

// software grid barrier: plain launch, graph-capture-safe.
// capacity argument: 256 blocks, >=2 blocks/CU capacity (38KB LDS, ~<=128 VGPR)
// on 256 CUs -> all blocks resident -> no deadlock. Bounded spin as a fuse.
__device__ __forceinline__ void gbar(unsigned* cnt) {
  __threadfence();                 // release: all threads drain stores (+L2 wb)
  __syncthreads();
  if (threadIdx.x == 0) {
    unsigned ticket = atomicAdd(cnt, 1u);            // device-scope
    unsigned target = ((ticket >> 8) + 1u) << 8;     // (gen+1)*256
    unsigned spins = 0;
    while (__hip_atomic_load(cnt, __ATOMIC_RELAXED, __HIP_MEMORY_SCOPE_AGENT) < target) {
      __builtin_amdgcn_s_sleep(1);
      if (++spins > 2000000u) break;                 // fuse: fail loud, not hung
    }
  }
  __syncthreads();
  __threadfence();                 // acquire: invalidate stale cached lines
}

// ---------- one-time kernels ----------
__global__ void k_init(float* __restrict__ ws) {   // legacy state
  int i = blockIdx.x * blockDim.x + threadIdx.x;
  if (i < 3 * HB) { ws[OFF_H + i] = 0.f; ws[OFF_C + i] = 0.f; }
  if (i < KV * B) ws[OFF_CTX + i] = 0.f;
  if (i < B)      ws[OFF_Z + i] = 1.f;
}

__global__ void k_init2(float* __restrict__ ws) {  // new-path state
  int i = blockIdx.x * blockDim.x + threadIdx.x;
  if (i < 64)      ws[OFF_H + i]    = 0.f;                    // barrier counters
  if (i < 4 * HB)  ws[NOFF_H01 + i] = 0.f;
  if (i < 3 * HB)  ws[NOFF_C + i]   = 0.f;
  if (i < HB)      ws[NOFF_H2 + i]  = 0.f;                    // h2 slot 0
  if (i < (long)(L + 1) * KVB) ws[NOFF_CTXA + i] = 0.f;       // atomic targets
  if (i < (L + 1) * B) ws[NOFF_ZA + i] = (i < B) ? 1.f : 0.f;
}

__global__ void k_embed(const int* __restrict__ labels, const float* __restrict__ emb,
                        float* __restrict__ xembT) {
  int i = blockIdx.x * blockDim.x + threadIdx.x;
  if (i >= L * E * B) return;
  int b = i & 63, e = (i >> 6) & 255, l = i >> 14;
  int lab = labels[l * B + b];
  xembT[i] = emb[lab * E + e];
}

__global__ void k_cvt(const float4* __restrict__ src, ushort4* __restrict__ dst, int n4) {
  int i = blockIdx.x * blockDim.x + threadIdx.x;
  int stride = gridDim.x * blockDim.x;
  for (int k = i; k < n4; k += stride) {
    float4 v = src[k];
    ushort4 o;
    o.x = f2bf(v.x); o.y = f2bf(v.y); o.z = f2bf(v.z); o.w = f2bf(v.w);
    dst[k] = o;
  }
}

// ---------- persistent fused decoder (plain launch + software barrier) ----------
// grid 256 blocks x 512 threads; block bi owns gate column j = bi for all 3
// LSTM cells (weight rows staged in LDS once), and attention batch b = bi>>2
// with interleaved row segments. 4 gbar() per step.
__global__ __launch_bounds__(512, 1) void k_mega(
    const float* __restrict__ wih0, const float* __restrict__ whh0,
    const float* __restrict__ bih0, const float* __restrict__ bhh0,
    const float* __restrict__ wihr, const float* __restrict__ whhr,
    const float* __restrict__ bihr, const float* __restrict__ bhhr,
    const ushort* __restrict__ kbf, const ushort* __restrict__ vbf,
    const int* __restrict__ lens, const float* __restrict__ xe,
    float* __restrict__ h01, float* __restrict__ h2a,
    float* __restrict__ ctxa, float* __restrict__ za,
    unsigned* __restrict__ bar) {
  const int bi  = blockIdx.x;
  const int tid = threadIdx.x;
  const int b   = tid & 63;
  const int q   = (tid >> 6) & 3;
  const int ks  = tid >> 8;

  __shared__ float wA[4][768];   // cell0: [q][ wih row 512 | whh row 256 ]
  __shared__ float wB[4][512];   // cell1: [q][ wih 256 | whh 256 ]
  __shared__ float wC[4][512];   // cell2
  __shared__ float bs[3][4];
  __shared__ float red[2][4][64];
  __shared__ float4 asum[8][64];
  __shared__ float az[8];

  for (int i = tid; i < 4 * 768; i += 512) {
    int qq = i / 768, o = i - qq * 768;
    wA[qq][o] = (o < 512) ? wih0[(long)(qq * H + bi) * 512 + o]
                          : whh0[(long)(qq * H + bi) * 256 + (o - 512)];
  }
  for (int i = tid; i < 4 * 512; i += 512) {
    int qq = i >> 9, o = i & 511;
    long row = qq * H + bi;
    wB[qq][o] = (o < 256) ? wihr[row * H + o] : whhr[row * H + (o - 256)];
    wC[qq][o] = (o < 256) ? wihr[(long)G * H + row * H + o]
                          : whhr[(long)G * H + row * H + (o - 256)];
  }
  if (tid < 4) {
    bs[0][tid] = bih0[tid * H + bi] + bhh0[tid * H + bi];
    bs[1][tid] = bihr[tid * H + bi] + bhhr[tid * H + bi];
    bs[2][tid] = bihr[G + tid * H + bi] + bhhr[G + tid * H + bi];
  }
  __syncthreads();

  const int ab    = bi >> 2;                       // attention batch
  const int aseg  = ((bi & 3) << 3) + (tid >> 6);  // 0..31 interleave phase
  const int alane = tid & 63;
  const int alen  = lens[ab];

  float c0 = 0.f, c1 = 0.f, c2 = 0.f;              // cell state, threads tid<64

  for (int t = 0; t < L; ++t) {
    const int cur = t & 1, nxt = cur ^ 1;
    const float* h0p = h01 + (long)cur * 2 * HB;
    const float* h1p = h0p + HB;
    float* h0n = h01 + (long)nxt * 2 * HB;
    float* h1n = h0n + HB;
    const float* xet  = xe + (long)t * E * B;
    const float* ctxc = ctxa + (long)t * KVB;
    const float* h2p  = h2a + (long)t * HB;
    float* h2n        = h2a + (long)(t + 1) * HB;

    // ---------- layer 0 ----------
    {
      float acc;
      if (ks == 0) {
        float s0 = 0.f, s1 = 0.f, s2 = 0.f, s3 = 0.f;
        const float4* wi4 = (const float4*)wA[q];
        #pragma unroll 4
        for (int k = 0; k < 256; k += 4) {
          float4 w = wi4[k >> 2];
          s0 += w.x * xet[(k)     * B + b];
          s1 += w.y * xet[(k + 1) * B + b];
          s2 += w.z * xet[(k + 2) * B + b];
          s3 += w.w * xet[(k + 3) * B + b];
        }
        float a0 = 0.f, a1 = 0.f;
        const float4* wh4 = (const float4*)(wA[q] + 512);
        #pragma unroll 4
        for (int k = 0; k < 128; k += 4) {
          float4 w = wh4[k >> 2];
          a0 += w.x * h0p[(k)     * B + b];
          a1 += w.y * h0p[(k + 1) * B + b];
          a0 += w.z * h0p[(k + 2) * B + b];
          a1 += w.w * h0p[(k + 3) * B + b];
        }
        acc = bs[0][q] + (s0 + s1) + (s2 + s3) + (a0 + a1);
      } else {
        float zz = 1.f / fmaxf(za[t * B + b], 1e-12f);
        float s0 = 0.f, s1 = 0.f, s2 = 0.f, s3 = 0.f;
        const float4* wi4 = (const float4*)(wA[q] + 256);
        #pragma unroll 4
        for (int k = 0; k < 256; k += 4) {
          float4 w = wi4[k >> 2];
          s0 += w.x * ctxc[(k)     * B + b];
          s1 += w.y * ctxc[(k + 1) * B + b];
          s2 += w.z * ctxc[(k + 2) * B + b];
          s3 += w.w * ctxc[(k + 3) * B + b];
        }
        float a0 = 0.f, a1 = 0.f;
        const float4* wh4 = (const float4*)(wA[q] + 640);
        #pragma unroll 4
        for (int k = 0; k < 128; k += 4) {
          float4 w = wh4[k >> 2];
          a0 += w.x * h0p[(128 + k) * B + b];
          a1 += w.y * h0p[(129 + k) * B + b];
          a0 += w.z * h0p[(130 + k) * B + b];
          a1 += w.w * h0p[(131 + k) * B + b];
        }
        acc = ((s0 + s1) + (s2 + s3)) * zz + (a0 + a1);
      }
      red[ks][q][b] = acc;
      __syncthreads();
      if (tid < 64) {
        float gi = red[0][0][tid] + red[1][0][tid];
        float gf = red[0][1][tid] + red[1][1][tid];
        float gg = red[0][2][tid] + red[1][2][tid];
        float go = red[0][3][tid] + red[1][3][tid];
        c0 = sigm(gf) * c0 + sigm(gi) * tanh_f(gg);
        h0n[bi * B + tid] = sigm(go) * tanh_f(c0);
      }
    }
    gbar(bar);

    // ---------- layer 1 ----------
    {
      const int k0 = ks << 7;
      float a1 = 0.f, a2 = 0.f, a3 = 0.f, a4 = 0.f;
      const float4* wi4 = (const float4*)(wB[q] + k0);
      const float4* wh4 = (const float4*)(wB[q] + 256 + k0);
      #pragma unroll 4
      for (int k = 0; k < 128; k += 4) {
        float4 wi = wi4[k >> 2];
        float4 wh = wh4[k >> 2];
        a1 += wi.x * h0n[(k0 + k)     * B + b];
        a2 += wi.y * h0n[(k0 + k + 1) * B + b];
        a1 += wi.z * h0n[(k0 + k + 2) * B + b];
        a2 += wi.w * h0n[(k0 + k + 3) * B + b];
        a3 += wh.x * h1p[(k0 + k)     * B + b];
        a4 += wh.y * h1p[(k0 + k + 1) * B + b];
        a3 += wh.z * h1p[(k0 + k + 2) * B + b];
        a4 += wh.w * h1p[(k0 + k + 3) * B + b];
      }
      red[ks][q][b] = (ks ? 0.f : bs[1][q]) + (a1 + a2) + (a3 + a4);
      __syncthreads();
      if (tid < 64) {
        float gi = red[0][0][tid] + red[1][0][tid];
        float gf = red[0][1][tid] + red[1][1][tid];
        float gg = red[0][2][tid] + red[1][2][tid];
        float go = red[0][3][tid] + red[1][3][tid];
        c1 = sigm(gf) * c1 + sigm(gi) * tanh_f(gg);
        h1n[bi * B + tid] = sigm(go) * tanh_f(c1);
      }
    }
    gbar(bar);

    // ---------- layer 2 ----------
    {
      const int k0 = ks << 7;
      float a1 = 0.f, a2 = 0.f, a3 = 0.f, a4 = 0.f;
      const float4* wi4 = (const float4*)(wC[q] + k0);
      const float4* wh4 = (const float4*)(wC[q] + 256 + k0);
      #pragma unroll 4
      for (int k = 0; k < 128; k += 4) {
        float4 wi = wi4[k >> 2];
        float4 wh = wh4[k >> 2];
        a1 += wi.x * h1n[(k0 + k)     * B + b];
        a2 += wi.y * h1n[(k0 + k + 1) * B + b];
        a1 += wi.z * h1n[(k0 + k + 2) * B + b];
        a2 += wi.w * h1n[(k0 + k + 3) * B + b];
        a3 += wh.x * h2p[(k0 + k)     * B + b];
        a4 += wh.y * h2p[(k0 + k + 1) * B + b];
        a3 += wh.z * h2p[(k0 + k + 2) * B + b];
        a4 += wh.w * h2p[(k0 + k + 3) * B + b];
      }
      red[ks][q][b] = (ks ? 0.f : bs[2][q]) + (a1 + a2) + (a3 + a4);
      __syncthreads();
      if (tid < 64) {
        float gi = red[0][0][tid] + red[1][0][tid];
        float gf = red[0][1][tid] + red[1][1][tid];
        float gg = red[0][2][tid] + red[1][2][tid];
        float go = red[0][3][tid] + red[1][3][tid];
        c2 = sigm(gf) * c2 + sigm(gi) * tanh_f(gg);
        h2n[bi * B + tid] = sigm(go) * tanh_f(c2);
      }
    }
    gbar(bar);

    // ---------- attention (interleaved rows, unnormalized exp) ----------
    {
      float* ctxn = ctxa + (long)(t + 1) * KVB;
      float q0 = h2n[(4 * alane + 0) * B + ab];
      float q1 = h2n[(4 * alane + 1) * B + ab];
      float q2 = h2n[(4 * alane + 2) * B + ab];
      float q3 = h2n[(4 * alane + 3) * B + ab];
      float a0 = 0.f, a1 = 0.f, a2 = 0.f, a3 = 0.f, zp = 0.f;
      for (int r = aseg; r < alen; r += 32) {
        size_t off = ((size_t)(ab * T + r)) * KV + 4 * alane;
        uint2 kd = *(const uint2*)(kbf + off);
        uint2 vd = *(const uint2*)(vbf + off);
        float e = bf2f(kd.x & 0xffffu) * q0
                + __uint_as_float(kd.x & 0xffff0000u) * q1
                + bf2f(kd.y & 0xffffu) * q2
                + __uint_as_float(kd.y & 0xffff0000u) * q3;
        #pragma unroll
        for (int o = 32; o; o >>= 1) e += __shfl_xor(e, o, 64);
        float w = __expf(fminf(e, 50.f));
        a0 += w * bf2f(vd.x & 0xffffu);
        a1 += w * __uint_as_float(vd.x & 0xffff0000u);
        a2 += w * bf2f(vd.y & 0xffffu);
        a3 += w * __uint_as_float(vd.y & 0xffff0000u);
        zp += w;
      }
      int wv = tid >> 6;
      asum[wv][alane] = make_float4(a0, a1, a2, a3);
      if (alane == 0) az[wv] = zp;
      __syncthreads();
      if (tid < 256) {
        const float* as = (const float*)asum;
        float s = as[tid]        + as[256 + tid]  + as[512 + tid]  + as[768 + tid]
                + as[1024 + tid] + as[1280 + tid] + as[1536 + tid] + as[1792 + tid];
        atomicAdd(&ctxn[tid * B + ab], s);
      }
      if (tid == 0) {
        atomicAdd(&za[(t + 1) * B + ab],
                  az[0] + az[1] + az[2] + az[3] + az[4] + az[5] + az[6] + az[7]);
      }
    }
    gbar(bar);
  }
}

// ---------- LSTM cells (legacy fallback) ----------
__global__ __launch_bounds__(512) void k_cell0(
    const float* __restrict__ wih, const float* __restrict__ whh,
    const float* __restrict__ bih, const float* __restrict__ bhh,
    const float* __restrict__ xe,
    const float* __restrict__ ctx, const float* __restrict__ Z,
    const float* __restrict__ hprev,
    float* __restrict__ hnew, float* __restrict__ cst) {
  int t = threadIdx.x;
  int b = t & 63, q = (t >> 6) & 3, ks = t >> 8;
  int j = blockIdx.x;
  int row = q * H + j;
  float acc = 0.f, s0 = 0.f, s1 = 0.f, s2 = 0.f, s3 = 0.f, a2 = 0.f;
  if (ks == 0) {
    acc = bih[row] + bhh[row];
    const float* wi = wih + (long)row * (E + KV);
    #pragma unroll 4
    for (int k = 0; k < E; k += 4) {
      s0 += wi[k]   * xe[(k)   * B + b];
      s1 += wi[k+1] * xe[(k+1) * B + b];
      s2 += wi[k+2] * xe[(k+2) * B + b];
      s3 += wi[k+3] * xe[(k+3) * B + b];
    }
    const float* wh = whh + (long)row * H;
    #pragma unroll 4
    for (int k = 0; k < 128; k += 2) {
      a2 += wh[k]   * hprev[(k)   * B + b];
      a2 += wh[k+1] * hprev[(k+1) * B + b];
    }
    acc += (s0 + s1) + (s2 + s3) + a2;
  } else {
    float zz = 1.f / fmaxf(Z[b], 1e-12f);
    const float* wi = wih + (long)row * (E + KV) + E;
    #pragma unroll 4
    for (int k = 0; k < KV; k += 4) {
      s0 += wi[k]   * ctx[(k)   * B + b];
      s1 += wi[k+1] * ctx[(k+1) * B + b];
      s2 += wi[k+2] * ctx[(k+2) * B + b];
      s3 += wi[k+3] * ctx[(k+3) * B + b];
    }
    const float* wh = whh + (long)row * H + 128;
    #pragma unroll 4
    for (int k = 0; k < 128; k += 2) {
      a2 += wh[k]   * hprev[(128 + k)     * B + b];
      a2 += wh[k+1] * hprev[(128 + k + 1) * B + b];
    }
    acc = ((s0 + s1) + (s2 + s3)) * zz + a2;
  }
  __shared__ float sh[2][4][64];
  sh[ks][q][b] = acc;
  __syncthreads();
  if (t < 64) {
    int bb = t;
    float gi = sh[0][0][bb] + sh[1][0][bb];
    float gf = sh[0][1][bb] + sh[1][1][bb];
    float gg = sh[0][2][bb] + sh[1][2][bb];
    float go = sh[0][3][bb] + sh[1][3][bb];
    float c = sigm(gf) * cst[j * B + bb] + sigm(gi) * tanh_f(gg);
    float h = sigm(go) * tanh_f(c);
    cst[j * B + bb] = c;
    hnew[j * B + bb] = h;
  }
}

__global__ __launch_bounds__(512) void k_cellr(
    const float* __restrict__ wih, const float* __restrict__ whh,
    const float* __restrict__ bih, const float* __restrict__ bhh,
    const float* __restrict__ hin, const float* __restrict__ hprevL,
    float* __restrict__ hnewL, float* __restrict__ cst,
    float* __restrict__ ctxn, float* __restrict__ Zn, float* __restrict__ m, int aux) {
  int t = threadIdx.x;
  int b = t & 63, q = (t >> 6) & 3, ks = t >> 8;
  int j = blockIdx.x;
  int row = q * H + j;
  if (aux) {
    int gid = blockIdx.x * 512 + t;
    if (gid < KV * B) ctxn[gid] = 0.f;
    if (gid < B) { Zn[gid] = 0.f; m[gid] = -3.4e38f; }
  }
  float acc = ks ? 0.f : (bih[row] + bhh[row]);
  float a1 = 0.f, a2 = 0.f, a3 = 0.f, a4 = 0.f;
  const float* wi = wih + (long)row * H + ks * 128;
  const float* wh = whh + (long)row * H + ks * 128;
  int k0 = ks * 128;
  #pragma unroll 4
  for (int k = 0; k < 128; k += 2) {
    a1 += wi[k]   * hin[(k0 + k)     * B + b];
    a2 += wi[k+1] * hin[(k0 + k + 1) * B + b];
    a3 += wh[k]   * hprevL[(k0 + k)     * B + b];
    a4 += wh[k+1] * hprevL[(k0 + k + 1) * B + b];
  }
  acc += (a1 + a2) + (a3 + a4);
  __shared__ float sh[2][4][64];
  sh[ks][q][b] = acc;
  __syncthreads();
  if (t < 64) {
    int bb = t;
    float gi = sh[0][0][bb] + sh[1][0][bb];
    float gf = sh[0][1][bb] + sh[1][1][bb];
    float gg = sh[0][2][bb] + sh[1][2][bb];
    float go = sh[0][3][bb] + sh[1][3][bb];
    float c = sigm(gf) * cst[j * B + bb] + sigm(gi) * tanh_f(gg);
    float h = sigm(go) * tanh_f(c);
    cst[j * B + bb] = c;
    hnewL[j * B + bb] = h;
  }
}

// ---------- deferred MLP head (new path) ----------
__global__ __launch_bounds__(256) void k_fc1c(
    const float* __restrict__ w, const float* __restrict__ bias,
    const float* __restrict__ h2a, const float* __restrict__ ctxa,
    const float* __restrict__ za, float* __restrict__ hidc, int t0) {
  int s = blockIdx.y;
  int t = t0 + s;
  const float* h2  = h2a  + (long)(t + 1) * HB;
  const float* ctx = ctxa + (long)(t + 1) * KVB;
  int tid = threadIdx.x;
  int b = tid & 63, jl = tid >> 6;
  int j = blockIdx.x * 4 + jl;
  float zz = 1.f / fmaxf(za[(t + 1) * B + b], 1e-12f);
  const float* wr = w + (long)j * (H + KV);
  float s0 = 0.f, s1 = 0.f, c0 = 0.f, c1 = 0.f;
  #pragma unroll 4
  for (int k = 0; k < 256; k += 2) {
    s0 += wr[k]       * h2[(k)   * B + b];
    s1 += wr[k+1]     * h2[(k+1) * B + b];
    c0 += wr[256 + k]   * ctx[(k)   * B + b];
    c1 += wr[256 + k+1] * ctx[(k+1) * B + b];
  }
  float acc = bias[j] + (s0 + s1) + (c0 + c1) * zz;
  hidc[((long)s * MH + j) * B + b] = fmaxf(acc, 0.f);
}

__global__ __launch_bounds__(64) void k_fc2c(
    const float* __restrict__ w, const float* __restrict__ bias,
    const float* __restrict__ hidc, float* __restrict__ out, int t0) {
  int s = blockIdx.y;
  int v = blockIdx.x;
  int b = threadIdx.x;
  const float* hid = hidc + (long)s * MH * B;
  const float* wr = w + (long)v * MH;
  float s0 = 0.f, s1 = 0.f, s2 = 0.f, s3 = 0.f;
  #pragma unroll 4
  for (int k = 0; k < MH; k += 4) {
    s0 += wr[k]   * hid[(k)   * B + b];
    s1 += wr[k+1] * hid[(k+1) * B + b];
    s2 += wr[k+2] * hid[(k+2) * B + b];
    s3 += wr[k+3] * hid[(k+3) * B + b];
  }
  out[((long)b * L + (t0 + s)) * V + v] = bias[v] + (s0 + s1) + (s2 + s3);
}

// ---------- legacy fallback extras ----------
template <int BF>
__global__ __launch_bounds__(256) void k_energy(
    const void* __restrict__ keyp, const float* __restrict__ h2,
    const int* __restrict__ lens, float* __restrict__ e, float* __restrict__ m) {
  int b = blockIdx.y;
  int len = lens[b];
  int wave = threadIdx.x >> 6, lane = threadIdx.x & 63;
  int t0 = (blockIdx.x * 4 + wave) * 16;
  if (t0 >= len) return;
  float h0 = h2[(4 * lane + 0) * B + b];
  float h1 = h2[(4 * lane + 1) * B + b];
  float h2v = h2[(4 * lane + 2) * B + b];
  float h3 = h2[(4 * lane + 3) * B + b];
  int tend = min(t0 + 16, len);
  float wmax = -3.4e38f;
  for (int t = t0; t < tend; t++) {
    float4 kv;
    if (BF) {
      const uint2* p = (const uint2*)((const ushort*)keyp + (size_t)(b * T + t) * KV + 4 * lane);
      uint2 d = *p;
      kv.x = bf2f(d.x & 0xffffu);
      kv.y = __uint_as_float(d.x & 0xffff0000u);
      kv.z = bf2f(d.y & 0xffffu);
      kv.w = __uint_as_float(d.y & 0xffff0000u);
    } else {
      kv = ((const float4*)((const float*)keyp + (size_t)(b * T + t) * KV))[lane];
    }
    float s = kv.x * h0 + kv.y * h1 + kv.z * h2v + kv.w * h3;
    #pragma unroll
    for (int off = 32; off; off >>= 1) s += __shfl_xor(s, off, 64);
    if (lane == 0) e[b * T + t] = s;
    wmax = fmaxf(wmax, s);
  }
  if (lane == 0) atomicMaxFloat(&m[b], wmax);
}

template <int BF>
__global__ __launch_bounds__(256) void k_pv(
    const void* __restrict__ valp, const float* __restrict__ e, const float* __restrict__ m,
    const int* __restrict__ lens, float* __restrict__ ctxn, float* __restrict__ Zn) {
  int b = blockIdx.y;
  int len = lens[b];
  int t0blk = blockIdx.x * 256;
  if (t0blk >= len) return;
  int wave = threadIdx.x >> 6, lane = threadIdx.x & 63;
  float mb = m[b];
  float a0 = 0.f, a1 = 0.f, a2 = 0.f, a3 = 0.f, zp = 0.f;
  int t0 = t0blk + wave * 64;
  int tend = min(t0 + 64, len);
  for (int t = t0; t < tend; t++) {
    float w = __expf(e[b * T + t] - mb);
    float4 vv;
    if (BF) {
      const uint2* p = (const uint2*)((const ushort*)valp + (size_t)(b * T + t) * KV + 4 * lane);
      uint2 d = *p;
      vv.x = bf2f(d.x & 0xffffu);
      vv.y = __uint_as_float(d.x & 0xffff0000u);
      vv.z = bf2f(d.y & 0xffffu);
      vv.w = __uint_as_float(d.y & 0xffff0000u);
    } else {
      vv = ((const float4*)((const float*)valp + (size_t)(b * T + t) * KV))[lane];
    }
    a0 += w * vv.x; a1 += w * vv.y; a2 += w * vv.z; a3 += w * vv.w;
    zp += w;
  }
  __shared__ float sh[4][256];
  __shared__ float shz[4];
  sh[wave][4 * lane + 0] = a0;
  sh[wave][4 * lane + 1] = a1;
  sh[wave][4 * lane + 2] = a2;
  sh[wave][4 * lane + 3] = a3;
  if (lane == 0) shz[wave] = zp;
  __syncthreads();
  if (wave == 0) {
    #pragma unroll
    for (int r = 0; r < 4; r++) {
      int d = lane * 4 + r;
      float s = sh[0][d] + sh[1][d] + sh[2][d] + sh[3][d];
      atomicAdd(&ctxn[d * B + b], s);
    }
    if (lane == 0) atomicAdd(&Zn[b], shz[0] + shz[1] + shz[2] + shz[3]);
  }
}

__global__ __launch_bounds__(256) void k_fc1(
    const float* __restrict__ w, const float* __restrict__ bias,
    const float* __restrict__ h2, const float* __restrict__ ctxn, const float* __restrict__ Zn,
    float* __restrict__ hid) {
  int t = threadIdx.x;
  int b = t & 63, jl = t >> 6;
  int j = blockIdx.x * 4 + jl;
  float zz = 1.f / fmaxf(Zn[b], 1e-12f);
  const float* wr = w + (long)j * (H + KV);
  float s0 = 0.f, s1 = 0.f, s2 = 0.f, s3 = 0.f, a2 = 0.f, a3 = 0.f;
  #pragma unroll 4
  for (int k = 0; k < H; k += 4) {
    s0 += wr[k]   * h2[(k)   * B + b];
    s1 += wr[k+1] * h2[(k+1) * B + b];
    s2 += wr[k+2] * h2[(k+2) * B + b];
    s3 += wr[k+3] * h2[(k+3) * B + b];
  }
  #pragma unroll 4
  for (int k = 0; k < KV; k += 2) {
    a2 += wr[H + k]     * ctxn[(k)   * B + b];
    a3 += wr[H + k + 1] * ctxn[(k+1) * B + b];
  }
  float acc = bias[j] + (s0 + s1) + (s2 + s3) + (a2 + a3) * zz;
  hid[j * B + b] = fmaxf(acc, 0.f);
}

__global__ __launch_bounds__(64) void k_fc2(
    const float* __restrict__ w, const float* __restrict__ bias,
    const float* __restrict__ hid, float* __restrict__ out, int step) {
  int b = threadIdx.x;
  int v = blockIdx.x;
  const float* wr = w + (long)v * MH;
  float s0 = 0.f, s1 = 0.f, s2 = 0.f, s3 = 0.f;
  #pragma unroll 4
  for (int k = 0; k < MH; k += 4) {
    s0 += wr[k]   * hid[(k)   * B + b];
    s1 += wr[k+1] * hid[(k+1) * B + b];
    s2 += wr[k+2] * hid[(k+2) * B + b];
    s3 += wr[k+3] * hid[(k+3) * B + b];
  }
  out[((long)b * L + step) * V + v] = bias[v] + (s0 + s1) + (s2 + s3);
}

static void launch_legacy(const float* key, const float* value, const int* lens,
                          const float* w_ih0, const float* w_hh0,
                          const float* b_ih0, const float* b_hh0,
                          const float* w_ihr, const float* w_hhr,
                          const float* b_ihr, const float* b_hhr,
                          const float* fc1_w, const float* fc1_b,
                          const float* fc2_w, const float* fc2_b,
                          float* out, float* ws,
                          const ushort* kbf, const ushort* vbf, bool bf,
                          hipStream_t stream) {
  float* hbuf = ws + OFF_H;
  float* cbuf = ws + OFF_C;
  float* ctxb = ws + OFF_CTX;
  float* Zb   = ws + OFF_Z;
  float* mb   = ws + OFF_M;
  float* eb   = ws + OFF_E;
  float* hid  = ws + OFF_HID;
  float* xe   = ws + OFF_XE;
  for (int t = 0; t < L; t++) {
    int cur = t & 1, nxt = cur ^ 1;
    float* hprev = hbuf + (long)cur * 3 * HB;
    float* hnew  = hbuf + (long)nxt * 3 * HB;
    float* ctxc  = ctxb + (long)cur * KV * B;
    float* ctxn  = ctxb + (long)nxt * KV * B;
    float* Zc = Zb + cur * B;
    float* Zn = Zb + nxt * B;

    k_cell0<<<H, 512, 0, stream>>>(w_ih0, w_hh0, b_ih0, b_hh0,
                                   xe + (long)t * E * B, ctxc, Zc,
                                   hprev, hnew, cbuf);
    k_cellr<<<H, 512, 0, stream>>>(w_ihr, w_hhr, b_ihr, b_hhr,
                                   hnew, hprev + HB, hnew + HB, cbuf + HB,
                                   ctxn, Zn, mb, 1);
    k_cellr<<<H, 512, 0, stream>>>(w_ihr + (long)G * H, w_hhr + (long)G * H,
                                   b_ihr + G, b_hhr + G,
                                   hnew + HB, hprev + 2 * HB, hnew + 2 * HB, cbuf + 2 * HB,
                                   nullptr, nullptr, nullptr, 0);
    if (bf) {
      k_energy<1><<<dim3(T / 64, B), 256, 0, stream>>>(kbf, hnew + 2 * HB, lens, eb, mb);
      k_pv<1><<<dim3(T / 256, B), 256, 0, stream>>>(vbf, eb, mb, lens, ctxn, Zn);
    } else {
      k_energy<0><<<dim3(T / 64, B), 256, 0, stream>>>(key, hnew + 2 * HB, lens, eb, mb);
      k_pv<0><<<dim3(T / 256, B), 256, 0, stream>>>(value, eb, mb, lens, ctxn, Zn);
    }
    k_fc1<<<MH / 4, 256, 0, stream>>>(fc1_w, fc1_b, hnew + 2 * HB, ctxn, Zn, hid);
    k_fc2<<<V, 64, 0, stream>>>(fc2_w, fc2_b, hid, out, t);
  }
}

extern "C" void kernel_launch(void* const* d_in, const int* in_sizes, int n_in,
                              void* d_out, int out_size, void* d_ws, size_t ws_size,
                              hipStream_t stream) {
  const float* key    = (const float*)d_in[0];
  const float* value  = (const float*)d_in[1];
  const int*   labels = (const int*)d_in[2];
  const int*   lens   = (const int*)d_in[3];
  const float* emb    = (const float*)d_in[4];
  const float* w_ih0  = (const float*)d_in[5];
  const float* w_hh0  = (const float*)d_in[6];
  const float* b_ih0  = (const float*)d_in[7];
  const float* b_hh0  = (const float*)d_in[8];
  const float* w_ihr  = (const float*)d_in[9];
  const float* w_hhr  = (const float*)d_in[10];
  const float* b_ihr  = (const float*)d_in[11];
  const float* b_hhr  = (const float*)d_in[12];
  const float* fc1_w  = (const float*)d_in[13];
  const float* fc1_b  = (const float*)d_in[14];
  const float* fc2_w  = (const float*)d_in[15];
  const float* fc2_b  = (const float*)d_in[16];
  float* out = (float*)d_out;
  float* ws  = (float*)d_ws;

  bool bf      = ((long)ws_size >= NEED_BF);
  bool newpath = ((long)ws_size >= NEED_NEW);
  ushort* kbf = (ushort*)((char*)d_ws + FLOATBYTES);
  ushort* vbf = kbf + KVELEMS;

  k_embed<<<(L * E * B + 255) / 256, 256, 0, stream>>>(labels, emb, ws + OFF_XE);
  if (bf) {
    int n4 = (int)(KVELEMS >> 2);
    k_cvt<<<4096, 256, 0, stream>>>((const float4*)key, (ushort4*)kbf, n4);
    k_cvt<<<4096, 256, 0, stream>>>((const float4*)value, (ushort4*)vbf, n4);
  }

  if (newpath) {
    k_init2<<<(int)(((long)(L + 1) * KVB + 255) / 256), 256, 0, stream>>>(ws);
    float* h01  = ws + NOFF_H01;
    float* h2a  = ws + NOFF_H2;
    float* ctxa = ws + NOFF_CTXA;
    float* za   = ws + NOFF_ZA;
    float* hidc = ws + NOFF_HIDC;
    float* xep  = ws + OFF_XE;
    unsigned* bar = (unsigned*)(ws + OFF_H);

    k_mega<<<256, 512, 0, stream>>>(w_ih0, w_hh0, b_ih0, b_hh0,
                                    w_ihr, w_hhr, b_ihr, b_hhr,
                                    kbf, vbf, lens, xep,
                                    h01, h2a, ctxa, za, bar);

    for (int c = 0; c < L / CS; c++) {
      int t0 = c * CS;
      k_fc1c<<<dim3(MH / 4, CS), 256, 0, stream>>>(fc1_w, fc1_b, h2a, ctxa, za, hidc, t0);
      k_fc2c<<<dim3(V, CS), 64, 0, stream>>>(fc2_w, fc2_b, hidc, out, t0);
    }
  } else {
    k_init<<<(3 * HB + 255) / 256, 256, 0, stream>>>(ws);
    launch_legacy(key, value, lens, w_ih0, w_hh0, b_ih0, b_hh0,
                  w_ihr, w_hhr, b_ihr, b_hhr, fc1_w, fc1_b, fc2_w, fc2_b,
                  out, ws, kbf, vbf, bf, stream);
  }
}

// Round 3
// 15508.038 us; speedup vs baseline: 4.4127x; 4.4127x over previous
//
#include <hip/hip_runtime.h>
#include <hip/hip_bf16.h>

namespace {
constexpr int B  = 64;
constexpr int T  = 2048;
constexpr int L  = 200;
constexpr int H  = 256;
constexpr int KV = 256;
constexpr int E  = 256;
constexpr int V  = 33;
constexpr int MH = 512;
constexpr int G  = 4 * H;
constexpr int HB = H * B;       // 16384
constexpr int KVB = KV * B;     // 16384
constexpr int CS = 50;          // head chunk (steps)

// ---- legacy (round-0) float layout ----
constexpr long OFF_H   = 0;                        // legacy h dbuf; newpath reuses [0..511] as barrier
constexpr long OFF_C   = OFF_H  + 2L * 3 * HB;
constexpr long OFF_CTX = OFF_C  + 3L * HB;         // ctx double buffer [2][KV][B]
constexpr long OFF_Z   = OFF_CTX + 2L * KV * B;
constexpr long OFF_M   = OFF_Z  + 2L * B;
constexpr long OFF_E   = OFF_M  + B;
constexpr long OFF_HID = OFF_E  + (long)B * T;
constexpr long OFF_XE  = OFF_HID + (long)MH * B;   // xembT [L][E][B] (both paths)
constexpr long FLOATS_OLD = OFF_XE + (long)L * E * B;
constexpr long FLOATBYTES = FLOATS_OLD * 4;
constexpr long KVELEMS = (long)B * T * KV;         // 33,554,432
constexpr long NEED_BF = FLOATBYTES + 2 * KVELEMS * 2;   // legacy + bf16 KV

// ---- new-path extra region (after bf16 KV) ----
constexpr long NOFF      = NEED_BF / 4;            // float offset (16B aligned)
constexpr long NOFF_H01  = NOFF;                   // [2][2][H][B] layers 0,1 ping-pong
constexpr long NOFF_C    = NOFF_H01 + 4L * HB;     // [3][H][B]
constexpr long NOFF_H2   = NOFF_C   + 3L * HB;     // [L+1][H][B]
constexpr long NOFF_CTXA = NOFF_H2  + (long)(L + 1) * HB;   // [L+1][KV][B]
constexpr long NOFF_ZA   = NOFF_CTXA + (long)(L + 1) * KVB; // [L+1][B]
constexpr long NOFF_HIDC = NOFF_ZA  + (long)(L + 1) * B;    // [CS][MH][B]
constexpr long FLOATS_NEW = NOFF_HIDC + (long)CS * MH * B;
constexpr long NEED_NEW   = FLOATS_NEW * 4;        // ~182.1 MB
}

__device__ __forceinline__ float sigm(float x) { return 1.f / (1.f + __expf(-x)); }
__device__ __forceinline__ float tanh_f(float x) {
  float xc = fminf(fmaxf(x, -15.f), 15.f);
  float e2 = __expf(2.f * xc);
  return (e2 - 1.f) / (e2 + 1.f);
}
__device__ __forceinline__ ushort f2bf(float x) {
  unsigned u = __float_as_uint(x);
  unsigned r = (u + 0x7fffu + ((u >> 16) & 1u)) >> 16;
  return (ushort)r;
}
__device__ __forceinline__ float bf2f(unsigned v) { return __uint_as_float(v << 16); }

// device-coherent (L2-bypassing, sc1) scalar load/store for cross-block state.
__device__ __forceinline__ float gload(const float* p) {
  return __hip_atomic_load(p, __ATOMIC_RELAXED, __HIP_MEMORY_SCOPE_AGENT);
}
__device__ __forceinline__ void gstore(float* p, float v) {
  __hip_atomic_store(p, v, __ATOMIC_RELAXED, __HIP_MEMORY_SCOPE_AGENT);
}

__device__ __forceinline__ void atomicMaxFloat(float* p, float v) {
  int old = __float_as_int(*p);
  while (__int_as_float(old) < v) {
    int assumed = old;
    old = atomicCAS((int*)p, assumed, __float_as_int(v));
    if (old == assumed) break;
  }
}

// Fence-free grid barrier. Correctness model: all cross-block data moves via
// sc1 (agent-scope) load/store/atomics that bypass the non-coherent per-XCD
// L2, so no wbl2/inv fence is needed. __syncthreads() drains each wave's
// vmcnt(0) (compiler-enforced), ordering all stores before the arrival atomic.
// Arrival counter and release words live on separate cache lines; release is
// fanned out to 8 lines (32 pollers each) to avoid RMW/poll collisions.
__device__ __forceinline__ void gbar(unsigned* bar, unsigned gen) {
  __syncthreads();                       // all waves' stores drained (vmcnt 0)
  if (threadIdx.x == 0) {
    asm volatile("s_waitcnt vmcnt(0)" ::: "memory");
    __hip_atomic_fetch_add(bar, 1u, __ATOMIC_RELAXED, __HIP_MEMORY_SCOPE_AGENT);
    unsigned target = gen << 8;          // gen * 256 blocks
    unsigned spins = 0;
    if (blockIdx.x == 0) {
      while (__hip_atomic_load(bar, __ATOMIC_RELAXED, __HIP_MEMORY_SCOPE_AGENT) < target) {
        __builtin_amdgcn_s_sleep(2);
        if (++spins > 200000u) break;    // fuse: fail loud, not hung
      }
      #pragma unroll
      for (int i = 0; i < 8; ++i)
        __hip_atomic_store(bar + 64 + 32 * i, gen, __ATOMIC_RELAXED, __HIP_MEMORY_SCOPE_AGENT);
    } else {
      unsigned* rel = bar + 64 + 32 * (blockIdx.x >> 5);
      while (__hip_atomic_load(rel, __ATOMIC_RELAXED, __HIP_MEMORY_SCOPE_AGENT) < gen) {
        __builtin_amdgcn_s_sleep(2);
        if (++spins > 200000u) break;    // fuse
      }
    }
  }
  __syncthreads();
}

// ---------- one-time kernels ----------
__global__ void k_init(float* __restrict__ ws) {   // legacy state
  int i = blockIdx.x * blockDim.x + threadIdx.x;
  if (i < 3 * HB) { ws[OFF_H + i] = 0.f; ws[OFF_C + i] = 0.f; }
  if (i < KV * B) ws[OFF_CTX + i] = 0.f;
  if (i < B)      ws[OFF_Z + i] = 1.f;
}

__global__ void k_init2(float* __restrict__ ws) {  // new-path state
  int i = blockIdx.x * blockDim.x + threadIdx.x;
  if (i < 512)     ws[OFF_H + i]    = 0.f;                    // barrier lines
  if (i < 4 * HB)  ws[NOFF_H01 + i] = 0.f;
  if (i < 3 * HB)  ws[NOFF_C + i]   = 0.f;
  if (i < HB)      ws[NOFF_H2 + i]  = 0.f;                    // h2 slot 0
  if (i < (long)(L + 1) * KVB) ws[NOFF_CTXA + i] = 0.f;       // atomic targets
  if (i < (L + 1) * B) ws[NOFF_ZA + i] = (i < B) ? 1.f : 0.f;
}

__global__ void k_embed(const int* __restrict__ labels, const float* __restrict__ emb,
                        float* __restrict__ xembT) {
  int i = blockIdx.x * blockDim.x + threadIdx.x;
  if (i >= L * E * B) return;
  int b = i & 63, e = (i >> 6) & 255, l = i >> 14;
  int lab = labels[l * B + b];
  xembT[i] = emb[lab * E + e];
}

__global__ void k_cvt(const float4* __restrict__ src, ushort4* __restrict__ dst, int n4) {
  int i = blockIdx.x * blockDim.x + threadIdx.x;
  int stride = gridDim.x * blockDim.x;
  for (int k = i; k < n4; k += stride) {
    float4 v = src[k];
    ushort4 o;
    o.x = f2bf(v.x); o.y = f2bf(v.y); o.z = f2bf(v.z); o.w = f2bf(v.w);
    dst[k] = o;
  }
}

// ---------- persistent fused decoder (plain launch + fence-free barrier) ----------
// grid 256 blocks x 512 threads; block bi owns gate column j = bi for all 3
// LSTM cells (weight rows staged in LDS once), and attention batch b = bi>>2
// with interleaved row segments. 4 gbar() per step. All cross-block state
// (h0/h1/h2, ctx, za) moves via sc1 agent load/store or device atomics.
__global__ __launch_bounds__(512, 1) void k_mega(
    const float* __restrict__ wih0, const float* __restrict__ whh0,
    const float* __restrict__ bih0, const float* __restrict__ bhh0,
    const float* __restrict__ wihr, const float* __restrict__ whhr,
    const float* __restrict__ bihr, const float* __restrict__ bhhr,
    const ushort* __restrict__ kbf, const ushort* __restrict__ vbf,
    const int* __restrict__ lens, const float* __restrict__ xe,
    float* __restrict__ h01, float* __restrict__ h2a,
    float* __restrict__ ctxa, float* __restrict__ za,
    unsigned* __restrict__ bar) {
  const int bi  = blockIdx.x;
  const int tid = threadIdx.x;
  const int b   = tid & 63;
  const int q   = (tid >> 6) & 3;
  const int ks  = tid >> 8;

  __shared__ float wA[4][768];   // cell0: [q][ wih row 512 | whh row 256 ]
  __shared__ float wB[4][512];   // cell1: [q][ wih 256 | whh 256 ]
  __shared__ float wC[4][512];   // cell2
  __shared__ float bs[3][4];
  __shared__ float red[2][4][64];
  __shared__ float4 asum[8][64];
  __shared__ float az[8];

  for (int i = tid; i < 4 * 768; i += 512) {
    int qq = i / 768, o = i - qq * 768;
    wA[qq][o] = (o < 512) ? wih0[(long)(qq * H + bi) * 512 + o]
                          : whh0[(long)(qq * H + bi) * 256 + (o - 512)];
  }
  for (int i = tid; i < 4 * 512; i += 512) {
    int qq = i >> 9, o = i & 511;
    long row = qq * H + bi;
    wB[qq][o] = (o < 256) ? wihr[row * H + o] : whhr[row * H + (o - 256)];
    wC[qq][o] = (o < 256) ? wihr[(long)G * H + row * H + o]
                          : whhr[(long)G * H + row * H + (o - 256)];
  }
  if (tid < 4) {
    bs[0][tid] = bih0[tid * H + bi] + bhh0[tid * H + bi];
    bs[1][tid] = bihr[tid * H + bi] + bhhr[tid * H + bi];
    bs[2][tid] = bihr[G + tid * H + bi] + bhhr[G + tid * H + bi];
  }
  __syncthreads();

  const int ab    = bi >> 2;                       // attention batch
  const int aseg  = ((bi & 3) << 3) + (tid >> 6);  // 0..31 interleave phase
  const int alane = tid & 63;
  const int alen  = lens[ab];

  float c0 = 0.f, c1 = 0.f, c2 = 0.f;              // cell state, threads tid<64

  for (int t = 0; t < L; ++t) {
    const int cur = t & 1, nxt = cur ^ 1;
    const float* h0p = h01 + (long)cur * 2 * HB;
    const float* h1p = h0p + HB;
    float* h0n = h01 + (long)nxt * 2 * HB;
    float* h1n = h0n + HB;
    const float* xet  = xe + (long)t * E * B;
    const float* ctxc = ctxa + (long)t * KVB;
    const float* h2p  = h2a + (long)t * HB;
    float* h2n        = h2a + (long)(t + 1) * HB;

    // ---------- layer 0 ----------
    {
      float acc;
      if (ks == 0) {
        float s0 = 0.f, s1 = 0.f, s2 = 0.f, s3 = 0.f;
        const float4* wi4 = (const float4*)wA[q];
        #pragma unroll 4
        for (int k = 0; k < 256; k += 4) {
          float4 w = wi4[k >> 2];
          s0 += w.x * xet[(k)     * B + b];
          s1 += w.y * xet[(k + 1) * B + b];
          s2 += w.z * xet[(k + 2) * B + b];
          s3 += w.w * xet[(k + 3) * B + b];
        }
        float a0 = 0.f, a1 = 0.f;
        const float4* wh4 = (const float4*)(wA[q] + 512);
        #pragma unroll 4
        for (int k = 0; k < 128; k += 4) {
          float4 w = wh4[k >> 2];
          a0 += w.x * gload(&h0p[(k)     * B + b]);
          a1 += w.y * gload(&h0p[(k + 1) * B + b]);
          a0 += w.z * gload(&h0p[(k + 2) * B + b]);
          a1 += w.w * gload(&h0p[(k + 3) * B + b]);
        }
        acc = bs[0][q] + (s0 + s1) + (s2 + s3) + (a0 + a1);
      } else {
        float zz = 1.f / fmaxf(gload(&za[t * B + b]), 1e-12f);
        float s0 = 0.f, s1 = 0.f, s2 = 0.f, s3 = 0.f;
        const float4* wi4 = (const float4*)(wA[q] + 256);
        #pragma unroll 4
        for (int k = 0; k < 256; k += 4) {
          float4 w = wi4[k >> 2];
          s0 += w.x * gload(&ctxc[(k)     * B + b]);
          s1 += w.y * gload(&ctxc[(k + 1) * B + b]);
          s2 += w.z * gload(&ctxc[(k + 2) * B + b]);
          s3 += w.w * gload(&ctxc[(k + 3) * B + b]);
        }
        float a0 = 0.f, a1 = 0.f;
        const float4* wh4 = (const float4*)(wA[q] + 640);
        #pragma unroll 4
        for (int k = 0; k < 128; k += 4) {
          float4 w = wh4[k >> 2];
          a0 += w.x * gload(&h0p[(128 + k) * B + b]);
          a1 += w.y * gload(&h0p[(129 + k) * B + b]);
          a0 += w.z * gload(&h0p[(130 + k) * B + b]);
          a1 += w.w * gload(&h0p[(131 + k) * B + b]);
        }
        acc = ((s0 + s1) + (s2 + s3)) * zz + (a0 + a1);
      }
      red[ks][q][b] = acc;
      __syncthreads();
      if (tid < 64) {
        float gi = red[0][0][tid] + red[1][0][tid];
        float gf = red[0][1][tid] + red[1][1][tid];
        float gg = red[0][2][tid] + red[1][2][tid];
        float go = red[0][3][tid] + red[1][3][tid];
        c0 = sigm(gf) * c0 + sigm(gi) * tanh_f(gg);
        gstore(&h0n[bi * B + tid], sigm(go) * tanh_f(c0));
      }
    }
    gbar(bar, 4 * t + 1);

    // ---------- layer 1 ----------
    {
      const int k0 = ks << 7;
      float a1 = 0.f, a2 = 0.f, a3 = 0.f, a4 = 0.f;
      const float4* wi4 = (const float4*)(wB[q] + k0);
      const float4* wh4 = (const float4*)(wB[q] + 256 + k0);
      #pragma unroll 4
      for (int k = 0; k < 128; k += 4) {
        float4 wi = wi4[k >> 2];
        float4 wh = wh4[k >> 2];
        a1 += wi.x * gload(&h0n[(k0 + k)     * B + b]);
        a2 += wi.y * gload(&h0n[(k0 + k + 1) * B + b]);
        a1 += wi.z * gload(&h0n[(k0 + k + 2) * B + b]);
        a2 += wi.w * gload(&h0n[(k0 + k + 3) * B + b]);
        a3 += wh.x * gload(&h1p[(k0 + k)     * B + b]);
        a4 += wh.y * gload(&h1p[(k0 + k + 1) * B + b]);
        a3 += wh.z * gload(&h1p[(k0 + k + 2) * B + b]);
        a4 += wh.w * gload(&h1p[(k0 + k + 3) * B + b]);
      }
      red[ks][q][b] = (ks ? 0.f : bs[1][q]) + (a1 + a2) + (a3 + a4);
      __syncthreads();
      if (tid < 64) {
        float gi = red[0][0][tid] + red[1][0][tid];
        float gf = red[0][1][tid] + red[1][1][tid];
        float gg = red[0][2][tid] + red[1][2][tid];
        float go = red[0][3][tid] + red[1][3][tid];
        c1 = sigm(gf) * c1 + sigm(gi) * tanh_f(gg);
        gstore(&h1n[bi * B + tid], sigm(go) * tanh_f(c1));
      }
    }
    gbar(bar, 4 * t + 2);

    // ---------- layer 2 ----------
    {
      const int k0 = ks << 7;
      float a1 = 0.f, a2 = 0.f, a3 = 0.f, a4 = 0.f;
      const float4* wi4 = (const float4*)(wC[q] + k0);
      const float4* wh4 = (const float4*)(wC[q] + 256 + k0);
      #pragma unroll 4
      for (int k = 0; k < 128; k += 4) {
        float4 wi = wi4[k >> 2];
        float4 wh = wh4[k >> 2];
        a1 += wi.x * gload(&h1n[(k0 + k)     * B + b]);
        a2 += wi.y * gload(&h1n[(k0 + k + 1) * B + b]);
        a1 += wi.z * gload(&h1n[(k0 + k + 2) * B + b]);
        a2 += wi.w * gload(&h1n[(k0 + k + 3) * B + b]);
        a3 += wh.x * gload(&h2p[(k0 + k)     * B + b]);
        a4 += wh.y * gload(&h2p[(k0 + k + 1) * B + b]);
        a3 += wh.z * gload(&h2p[(k0 + k + 2) * B + b]);
        a4 += wh.w * gload(&h2p[(k0 + k + 3) * B + b]);
      }
      red[ks][q][b] = (ks ? 0.f : bs[2][q]) + (a1 + a2) + (a3 + a4);
      __syncthreads();
      if (tid < 64) {
        float gi = red[0][0][tid] + red[1][0][tid];
        float gf = red[0][1][tid] + red[1][1][tid];
        float gg = red[0][2][tid] + red[1][2][tid];
        float go = red[0][3][tid] + red[1][3][tid];
        c2 = sigm(gf) * c2 + sigm(gi) * tanh_f(gg);
        gstore(&h2n[bi * B + tid], sigm(go) * tanh_f(c2));
      }
    }
    gbar(bar, 4 * t + 3);

    // ---------- attention (interleaved rows, unnormalized exp) ----------
    {
      float* ctxn = ctxa + (long)(t + 1) * KVB;
      float q0 = gload(&h2n[(4 * alane + 0) * B + ab]);
      float q1 = gload(&h2n[(4 * alane + 1) * B + ab]);
      float q2 = gload(&h2n[(4 * alane + 2) * B + ab]);
      float q3 = gload(&h2n[(4 * alane + 3) * B + ab]);
      float a0 = 0.f, a1 = 0.f, a2 = 0.f, a3 = 0.f, zp = 0.f;
      for (int r = aseg; r < alen; r += 32) {
        size_t off = ((size_t)(ab * T + r)) * KV + 4 * alane;
        uint2 kd = *(const uint2*)(kbf + off);
        uint2 vd = *(const uint2*)(vbf + off);
        float e = bf2f(kd.x & 0xffffu) * q0
                + __uint_as_float(kd.x & 0xffff0000u) * q1
                + bf2f(kd.y & 0xffffu) * q2
                + __uint_as_float(kd.y & 0xffff0000u) * q3;
        #pragma unroll
        for (int o = 32; o; o >>= 1) e += __shfl_xor(e, o, 64);
        float w = __expf(fminf(e, 50.f));
        a0 += w * bf2f(vd.x & 0xffffu);
        a1 += w * __uint_as_float(vd.x & 0xffff0000u);
        a2 += w * bf2f(vd.y & 0xffffu);
        a3 += w * __uint_as_float(vd.y & 0xffff0000u);
        zp += w;
      }
      int wv = tid >> 6;
      asum[wv][alane] = make_float4(a0, a1, a2, a3);
      if (alane == 0) az[wv] = zp;
      __syncthreads();
      if (tid < 256) {
        const float* as = (const float*)asum;
        float s = as[tid]        + as[256 + tid]  + as[512 + tid]  + as[768 + tid]
                + as[1024 + tid] + as[1280 + tid] + as[1536 + tid] + as[1792 + tid];
        atomicAdd(&ctxn[tid * B + ab], s);
      }
      if (tid == 0) {
        atomicAdd(&za[(t + 1) * B + ab],
                  az[0] + az[1] + az[2] + az[3] + az[4] + az[5] + az[6] + az[7]);
      }
    }
    gbar(bar, 4 * t + 4);
  }
}

// ---------- LSTM cells (legacy fallback) ----------
__global__ __launch_bounds__(512) void k_cell0(
    const float* __restrict__ wih, const float* __restrict__ whh,
    const float* __restrict__ bih, const float* __restrict__ bhh,
    const float* __restrict__ xe,
    const float* __restrict__ ctx, const float* __restrict__ Z,
    const float* __restrict__ hprev,
    float* __restrict__ hnew, float* __restrict__ cst) {
  int t = threadIdx.x;
  int b = t & 63, q = (t >> 6) & 3, ks = t >> 8;
  int j = blockIdx.x;
  int row = q * H + j;
  float acc = 0.f, s0 = 0.f, s1 = 0.f, s2 = 0.f, s3 = 0.f, a2 = 0.f;
  if (ks == 0) {
    acc = bih[row] + bhh[row];
    const float* wi = wih + (long)row * (E + KV);
    #pragma unroll 4
    for (int k = 0; k < E; k += 4) {
      s0 += wi[k]   * xe[(k)   * B + b];
      s1 += wi[k+1] * xe[(k+1) * B + b];
      s2 += wi[k+2] * xe[(k+2) * B + b];
      s3 += wi[k+3] * xe[(k+3) * B + b];
    }
    const float* wh = whh + (long)row * H;
    #pragma unroll 4
    for (int k = 0; k < 128; k += 2) {
      a2 += wh[k]   * hprev[(k)   * B + b];
      a2 += wh[k+1] * hprev[(k+1) * B + b];
    }
    acc += (s0 + s1) + (s2 + s3) + a2;
  } else {
    float zz = 1.f / fmaxf(Z[b], 1e-12f);
    const float* wi = wih + (long)row * (E + KV) + E;
    #pragma unroll 4
    for (int k = 0; k < KV; k += 4) {
      s0 += wi[k]   * ctx[(k)   * B + b];
      s1 += wi[k+1] * ctx[(k+1) * B + b];
      s2 += wi[k+2] * ctx[(k+2) * B + b];
      s3 += wi[k+3] * ctx[(k+3) * B + b];
    }
    const float* wh = whh + (long)row * H + 128;
    #pragma unroll 4
    for (int k = 0; k < 128; k += 2) {
      a2 += wh[k]   * hprev[(128 + k)     * B + b];
      a2 += wh[k+1] * hprev[(128 + k + 1) * B + b];
    }
    acc = ((s0 + s1) + (s2 + s3)) * zz + a2;
  }
  __shared__ float sh[2][4][64];
  sh[ks][q][b] = acc;
  __syncthreads();
  if (t < 64) {
    int bb = t;
    float gi = sh[0][0][bb] + sh[1][0][bb];
    float gf = sh[0][1][bb] + sh[1][1][bb];
    float gg = sh[0][2][bb] + sh[1][2][bb];
    float go = sh[0][3][bb] + sh[1][3][bb];
    float c = sigm(gf) * cst[j * B + bb] + sigm(gi) * tanh_f(gg);
    float h = sigm(go) * tanh_f(c);
    cst[j * B + bb] = c;
    hnew[j * B + bb] = h;
  }
}

__global__ __launch_bounds__(512) void k_cellr(
    const float* __restrict__ wih, const float* __restrict__ whh,
    const float* __restrict__ bih, const float* __restrict__ bhh,
    const float* __restrict__ hin, const float* __restrict__ hprevL,
    float* __restrict__ hnewL, float* __restrict__ cst,
    float* __restrict__ ctxn, float* __restrict__ Zn, float* __restrict__ m, int aux) {
  int t = threadIdx.x;
  int b = t & 63, q = (t >> 6) & 3, ks = t >> 8;
  int j = blockIdx.x;
  int row = q * H + j;
  if (aux) {
    int gid = blockIdx.x * 512 + t;
    if (gid < KV * B) ctxn[gid] = 0.f;
    if (gid < B) { Zn[gid] = 0.f; m[gid] = -3.4e38f; }
  }
  float acc = ks ? 0.f : (bih[row] + bhh[row]);
  float a1 = 0.f, a2 = 0.f, a3 = 0.f, a4 = 0.f;
  const float* wi = wih + (long)row * H + ks * 128;
  const float* wh = whh + (long)row * H + ks * 128;
  int k0 = ks * 128;
  #pragma unroll 4
  for (int k = 0; k < 128; k += 2) {
    a1 += wi[k]   * hin[(k0 + k)     * B + b];
    a2 += wi[k+1] * hin[(k0 + k + 1) * B + b];
    a3 += wh[k]   * hprevL[(k0 + k)     * B + b];
    a4 += wh[k+1] * hprevL[(k0 + k + 1) * B + b];
  }
  acc += (a1 + a2) + (a3 + a4);
  __shared__ float sh[2][4][64];
  sh[ks][q][b] = acc;
  __syncthreads();
  if (t < 64) {
    int bb = t;
    float gi = sh[0][0][bb] + sh[1][0][bb];
    float gf = sh[0][1][bb] + sh[1][1][bb];
    float gg = sh[0][2][bb] + sh[1][2][bb];
    float go = sh[0][3][bb] + sh[1][3][bb];
    float c = sigm(gf) * cst[j * B + bb] + sigm(gi) * tanh_f(gg);
    float h = sigm(go) * tanh_f(c);
    cst[j * B + bb] = c;
    hnewL[j * B + bb] = h;
  }
}

// ---------- deferred MLP head (new path) ----------
__global__ __launch_bounds__(256) void k_fc1c(
    const float* __restrict__ w, const float* __restrict__ bias,
    const float* __restrict__ h2a, const float* __restrict__ ctxa,
    const float* __restrict__ za, float* __restrict__ hidc, int t0) {
  int s = blockIdx.y;
  int t = t0 + s;
  const float* h2  = h2a  + (long)(t + 1) * HB;
  const float* ctx = ctxa + (long)(t + 1) * KVB;
  int tid = threadIdx.x;
  int b = tid & 63, jl = tid >> 6;
  int j = blockIdx.x * 4 + jl;
  float zz = 1.f / fmaxf(za[(t + 1) * B + b], 1e-12f);
  const float* wr = w + (long)j * (H + KV);
  float s0 = 0.f, s1 = 0.f, c0 = 0.f, c1 = 0.f;
  #pragma unroll 4
  for (int k = 0; k < 256; k += 2) {
    s0 += wr[k]       * h2[(k)   * B + b];
    s1 += wr[k+1]     * h2[(k+1) * B + b];
    c0 += wr[256 + k]   * ctx[(k)   * B + b];
    c1 += wr[256 + k+1] * ctx[(k+1) * B + b];
  }
  float acc = bias[j] + (s0 + s1) + (c0 + c1) * zz;
  hidc[((long)s * MH + j) * B + b] = fmaxf(acc, 0.f);
}

__global__ __launch_bounds__(64) void k_fc2c(
    const float* __restrict__ w, const float* __restrict__ bias,
    const float* __restrict__ hidc, float* __restrict__ out, int t0) {
  int s = blockIdx.y;
  int v = blockIdx.x;
  int b = threadIdx.x;
  const float* hid = hidc + (long)s * MH * B;
  const float* wr = w + (long)v * MH;
  float s0 = 0.f, s1 = 0.f, s2 = 0.f, s3 = 0.f;
  #pragma unroll 4
  for (int k = 0; k < MH; k += 4) {
    s0 += wr[k]   * hid[(k)   * B + b];
    s1 += wr[k+1] * hid[(k+1) * B + b];
    s2 += wr[k+2] * hid[(k+2) * B + b];
    s3 += wr[k+3] * hid[(k+3) * B + b];
  }
  out[((long)b * L + (t0 + s)) * V + v] = bias[v] + (s0 + s1) + (s2 + s3);
}

// ---------- legacy fallback extras ----------
template <int BF>
__global__ __launch_bounds__(256) void k_energy(
    const void* __restrict__ keyp, const float* __restrict__ h2,
    const int* __restrict__ lens, float* __restrict__ e, float* __restrict__ m) {
  int b = blockIdx.y;
  int len = lens[b];
  int wave = threadIdx.x >> 6, lane = threadIdx.x & 63;
  int t0 = (blockIdx.x * 4 + wave) * 16;
  if (t0 >= len) return;
  float h0 = h2[(4 * lane + 0) * B + b];
  float h1 = h2[(4 * lane + 1) * B + b];
  float h2v = h2[(4 * lane + 2) * B + b];
  float h3 = h2[(4 * lane + 3) * B + b];
  int tend = min(t0 + 16, len);
  float wmax = -3.4e38f;
  for (int t = t0; t < tend; t++) {
    float4 kv;
    if (BF) {
      const uint2* p = (const uint2*)((const ushort*)keyp + (size_t)(b * T + t) * KV + 4 * lane);
      uint2 d = *p;
      kv.x = bf2f(d.x & 0xffffu);
      kv.y = __uint_as_float(d.x & 0xffff0000u);
      kv.z = bf2f(d.y & 0xffffu);
      kv.w = __uint_as_float(d.y & 0xffff0000u);
    } else {
      kv = ((const float4*)((const float*)keyp + (size_t)(b * T + t) * KV))[lane];
    }
    float s = kv.x * h0 + kv.y * h1 + kv.z * h2v + kv.w * h3;
    #pragma unroll
    for (int off = 32; off; off >>= 1) s += __shfl_xor(s, off, 64);
    if (lane == 0) e[b * T + t] = s;
    wmax = fmaxf(wmax, s);
  }
  if (lane == 0) atomicMaxFloat(&m[b], wmax);
}

template <int BF>
__global__ __launch_bounds__(256) void k_pv(
    const void* __restrict__ valp, const float* __restrict__ e, const float* __restrict__ m,
    const int* __restrict__ lens, float* __restrict__ ctxn, float* __restrict__ Zn) {
  int b = blockIdx.y;
  int len = lens[b];
  int t0blk = blockIdx.x * 256;
  if (t0blk >= len) return;
  int wave = threadIdx.x >> 6, lane = threadIdx.x & 63;
  float mb = m[b];
  float a0 = 0.f, a1 = 0.f, a2 = 0.f, a3 = 0.f, zp = 0.f;
  int t0 = t0blk + wave * 64;
  int tend = min(t0 + 64, len);
  for (int t = t0; t < tend; t++) {
    float w = __expf(e[b * T + t] - mb);
    float4 vv;
    if (BF) {
      const uint2* p = (const uint2*)((const ushort*)valp + (size_t)(b * T + t) * KV + 4 * lane);
      uint2 d = *p;
      vv.x = bf2f(d.x & 0xffffu);
      vv.y = __uint_as_float(d.x & 0xffff0000u);
      vv.z = bf2f(d.y & 0xffffu);
      vv.w = __uint_as_float(d.y & 0xffff0000u);
    } else {
      vv = ((const float4*)((const float*)valp + (size_t)(b * T + t) * KV))[lane];
    }
    a0 += w * vv.x; a1 += w * vv.y; a2 += w * vv.z; a3 += w * vv.w;
    zp += w;
  }
  __shared__ float sh[4][256];
  __shared__ float shz[4];
  sh[wave][4 * lane + 0] = a0;
  sh[wave][4 * lane + 1] = a1;
  sh[wave][4 * lane + 2] = a2;
  sh[wave][4 * lane + 3] = a3;
  if (lane == 0) shz[wave] = zp;
  __syncthreads();
  if (wave == 0) {
    #pragma unroll
    for (int r = 0; r < 4; r++) {
      int d = lane * 4 + r;
      float s = sh[0][d] + sh[1][d] + sh[2][d] + sh[3][d];
      atomicAdd(&ctxn[d * B + b], s);
    }
    if (lane == 0) atomicAdd(&Zn[b], shz[0] + shz[1] + shz[2] + shz[3]);
  }
}

__global__ __launch_bounds__(256) void k_fc1(
    const float* __restrict__ w, const float* __restrict__ bias,
    const float* __restrict__ h2, const float* __restrict__ ctxn, const float* __restrict__ Zn,
    float* __restrict__ hid) {
  int t = threadIdx.x;
  int b = t & 63, jl = t >> 6;
  int j = blockIdx.x * 4 + jl;
  float zz = 1.f / fmaxf(Zn[b], 1e-12f);
  const float* wr = w + (long)j * (H + KV);
  float s0 = 0.f, s1 = 0.f, s2 = 0.f, s3 = 0.f, a2 = 0.f, a3 = 0.f;
  #pragma unroll 4
  for (int k = 0; k < H; k += 4) {
    s0 += wr[k]   * h2[(k)   * B + b];
    s1 += wr[k+1] * h2[(k+1) * B + b];
    s2 += wr[k+2] * h2[(k+2) * B + b];
    s3 += wr[k+3] * h2[(k+3) * B + b];
  }
  #pragma unroll 4
  for (int k = 0; k < KV; k += 2) {
    a2 += wr[H + k]     * ctxn[(k)   * B + b];
    a3 += wr[H + k + 1] * ctxn[(k+1) * B + b];
  }
  float acc = bias[j] + (s0 + s1) + (s2 + s3) + (a2 + a3) * zz;
  hid[j * B + b] = fmaxf(acc, 0.f);
}

__global__ __launch_bounds__(64) void k_fc2(
    const float* __restrict__ w, const float* __restrict__ bias,
    const float* __restrict__ hid, float* __restrict__ out, int step) {
  int b = threadIdx.x;
  int v = blockIdx.x;
  const float* wr = w + (long)v * MH;
  float s0 = 0.f, s1 = 0.f, s2 = 0.f, s3 = 0.f;
  #pragma unroll 4
  for (int k = 0; k < MH; k += 4) {
    s0 += wr[k]   * hid[(k)   * B + b];
    s1 += wr[k+1] * hid[(k+1) * B + b];
    s2 += wr[k+2] * hid[(k+2) * B + b];
    s3 += wr[k+3] * hid[(k+3) * B + b];
  }
  out[((long)b * L + step) * V + v] = bias[v] + (s0 + s1) + (s2 + s3);
}

static void launch_legacy(const float* key, const float* value, const int* lens,
                          const float* w_ih0, const float* w_hh0,
                          const float* b_ih0, const float* b_hh0,
                          const float* w_ihr, const float* w_hhr,
                          const float* b_ihr, const float* b_hhr,
                          const float* fc1_w, const float* fc1_b,
                          const float* fc2_w, const float* fc2_b,
                          float* out, float* ws,
                          const ushort* kbf, const ushort* vbf, bool bf,
                          hipStream_t stream) {
  float* hbuf = ws + OFF_H;
  float* cbuf = ws + OFF_C;
  float* ctxb = ws + OFF_CTX;
  float* Zb   = ws + OFF_Z;
  float* mb   = ws + OFF_M;
  float* eb   = ws + OFF_E;
  float* hid  = ws + OFF_HID;
  float* xe   = ws + OFF_XE;
  for (int t = 0; t < L; t++) {
    int cur = t & 1, nxt = cur ^ 1;
    float* hprev = hbuf + (long)cur * 3 * HB;
    float* hnew  = hbuf + (long)nxt * 3 * HB;
    float* ctxc  = ctxb + (long)cur * KV * B;
    float* ctxn  = ctxb + (long)nxt * KV * B;
    float* Zc = Zb + cur * B;
    float* Zn = Zb + nxt * B;

    k_cell0<<<H, 512, 0, stream>>>(w_ih0, w_hh0, b_ih0, b_hh0,
                                   xe + (long)t * E * B, ctxc, Zc,
                                   hprev, hnew, cbuf);
    k_cellr<<<H, 512, 0, stream>>>(w_ihr, w_hhr, b_ihr, b_hhr,
                                   hnew, hprev + HB, hnew + HB, cbuf + HB,
                                   ctxn, Zn, mb, 1);
    k_cellr<<<H, 512, 0, stream>>>(w_ihr + (long)G * H, w_hhr + (long)G * H,
                                   b_ihr + G, b_hhr + G,
                                   hnew + HB, hprev + 2 * HB, hnew + 2 * HB, cbuf + 2 * HB,
                                   nullptr, nullptr, nullptr, 0);
    if (bf) {
      k_energy<1><<<dim3(T / 64, B), 256, 0, stream>>>(kbf, hnew + 2 * HB, lens, eb, mb);
      k_pv<1><<<dim3(T / 256, B), 256, 0, stream>>>(vbf, eb, mb, lens, ctxn, Zn);
    } else {
      k_energy<0><<<dim3(T / 64, B), 256, 0, stream>>>(key, hnew + 2 * HB, lens, eb, mb);
      k_pv<0><<<dim3(T / 256, B), 256, 0, stream>>>(value, eb, mb, lens, ctxn, Zn);
    }
    k_fc1<<<MH / 4, 256, 0, stream>>>(fc1_w, fc1_b, hnew + 2 * HB, ctxn, Zn, hid);
    k_fc2<<<V, 64, 0, stream>>>(fc2_w, fc2_b, hid, out, t);
  }
}

extern "C" void kernel_launch(void* const* d_in, const int* in_sizes, int n_in,
                              void* d_out, int out_size, void* d_ws, size_t ws_size,
                              hipStream_t stream) {
  const float* key    = (const float*)d_in[0];
  const float* value  = (const float*)d_in[1];
  const int*   labels = (const int*)d_in[2];
  const int*   lens   = (const int*)d_in[3];
  const float* emb    = (const float*)d_in[4];
  const float* w_ih0  = (const float*)d_in[5];
  const float* w_hh0  = (const float*)d_in[6];
  const float* b_ih0  = (const float*)d_in[7];
  const float* b_hh0  = (const float*)d_in[8];
  const float* w_ihr  = (const float*)d_in[9];
  const float* w_hhr  = (const float*)d_in[10];
  const float* b_ihr  = (const float*)d_in[11];
  const float* b_hhr  = (const float*)d_in[12];
  const float* fc1_w  = (const float*)d_in[13];
  const float* fc1_b  = (const float*)d_in[14];
  const float* fc2_w  = (const float*)d_in[15];
  const float* fc2_b  = (const float*)d_in[16];
  float* out = (float*)d_out;
  float* ws  = (float*)d_ws;

  bool bf      = ((long)ws_size >= NEED_BF);
  bool newpath = ((long)ws_size >= NEED_NEW);
  ushort* kbf = (ushort*)((char*)d_ws + FLOATBYTES);
  ushort* vbf = kbf + KVELEMS;

  k_embed<<<(L * E * B + 255) / 256, 256, 0, stream>>>(labels, emb, ws + OFF_XE);
  if (bf) {
    int n4 = (int)(KVELEMS >> 2);
    k_cvt<<<4096, 256, 0, stream>>>((const float4*)key, (ushort4*)kbf, n4);
    k_cvt<<<4096, 256, 0, stream>>>((const float4*)value, (ushort4*)vbf, n4);
  }

  if (newpath) {
    k_init2<<<(int)(((long)(L + 1) * KVB + 255) / 256), 256, 0, stream>>>(ws);
    float* h01  = ws + NOFF_H01;
    float* h2a  = ws + NOFF_H2;
    float* ctxa = ws + NOFF_CTXA;
    float* za   = ws + NOFF_ZA;
    float* hidc = ws + NOFF_HIDC;
    float* xep  = ws + OFF_XE;
    unsigned* bar = (unsigned*)(ws + OFF_H);

    k_mega<<<256, 512, 0, stream>>>(w_ih0, w_hh0, b_ih0, b_hh0,
                                    w_ihr, w_hhr, b_ihr, b_hhr,
                                    kbf, vbf, lens, xep,
                                    h01, h2a, ctxa, za, bar);

    for (int c = 0; c < L / CS; c++) {
      int t0 = c * CS;
      k_fc1c<<<dim3(MH / 4, CS), 256, 0, stream>>>(fc1_w, fc1_b, h2a, ctxa, za, hidc, t0);
      k_fc2c<<<dim3(V, CS), 64, 0, stream>>>(fc2_w, fc2_b, hidc, out, t0);
    }
  } else {
    k_init<<<(3 * HB + 255) / 256, 256, 0, stream>>>(ws);
    launch_legacy(key, value, lens, w_ih0, w_hh0, b_ih0, b_hh0,
                  w_ihr, w_hhr, b_ihr, b_hhr, fc1_w, fc1_b, fc2_w, fc2_b,
                  out, ws, kbf, vbf, bf, stream);
  }
}

// Round 5
// 14483.116 us; speedup vs baseline: 4.7250x; 1.0708x over previous
//
#include <hip/hip_runtime.h>
#include <hip/hip_bf16.h>

namespace {
constexpr int B  = 64;
constexpr int T  = 2048;
constexpr int L  = 200;
constexpr int H  = 256;
constexpr int KV = 256;
constexpr int E  = 256;
constexpr int V  = 33;
constexpr int MH = 512;
constexpr int G  = 4 * H;
constexpr int HB = H * B;       // 16384
constexpr int KVB = KV * B;     // 16384
constexpr int CS = 50;          // head chunk (steps)

// ---- legacy (round-0) float layout ----
constexpr long OFF_H   = 0;                        // legacy h dbuf; newpath reuses [0..2047] as barrier
constexpr long OFF_C   = OFF_H  + 2L * 3 * HB;
constexpr long OFF_CTX = OFF_C  + 3L * HB;         // ctx double buffer [2][KV][B]
constexpr long OFF_Z   = OFF_CTX + 2L * KV * B;
constexpr long OFF_M   = OFF_Z  + 2L * B;
constexpr long OFF_E   = OFF_M  + B;
constexpr long OFF_HID = OFF_E  + (long)B * T;
constexpr long OFF_XE  = OFF_HID + (long)MH * B;   // xembT [L][E][B] (both paths)
constexpr long FLOATS_OLD = OFF_XE + (long)L * E * B;
constexpr long FLOATBYTES = FLOATS_OLD * 4;
constexpr long KVELEMS = (long)B * T * KV;         // 33,554,432
constexpr long NEED_BF = FLOATBYTES + 2 * KVELEMS * 2;   // legacy + bf16 KV

// ---- new-path extra region (after bf16 KV) ----
constexpr long NOFF      = NEED_BF / 4;            // float offset (16B aligned)
constexpr long NOFF_H01  = NOFF;                   // [2][2][H][B] layers 0,1 ping-pong
constexpr long NOFF_C    = NOFF_H01 + 4L * HB;     // [3][H][B]
constexpr long NOFF_H2   = NOFF_C   + 3L * HB;     // [L+1][H][B]
constexpr long NOFF_CTXA = NOFF_H2  + (long)(L + 1) * HB;   // [L+1][KV][B]
constexpr long NOFF_ZA   = NOFF_CTXA + (long)(L + 1) * KVB; // [L+1][B]
constexpr long NOFF_HIDC = NOFF_ZA  + (long)(L + 1) * B;    // [CS][MH][B]
constexpr long FLOATS_NEW = NOFF_HIDC + (long)CS * MH * B;
constexpr long NEED_NEW   = FLOATS_NEW * 4;        // ~182.1 MB
}

__device__ __forceinline__ float sigm(float x) { return 1.f / (1.f + __expf(-x)); }
__device__ __forceinline__ float tanh_f(float x) {
  float xc = fminf(fmaxf(x, -15.f), 15.f);
  float e2 = __expf(2.f * xc);
  return (e2 - 1.f) / (e2 + 1.f);
}
__device__ __forceinline__ ushort f2bf(float x) {
  unsigned u = __float_as_uint(x);
  unsigned r = (u + 0x7fffu + ((u >> 16) & 1u)) >> 16;
  return (ushort)r;
}
__device__ __forceinline__ float bf2f(unsigned v) { return __uint_as_float(v << 16); }

// device-coherent (L2-bypassing, sc1) scalar load/store for cross-block state.
__device__ __forceinline__ float gload(const float* p) {
  return __hip_atomic_load(p, __ATOMIC_RELAXED, __HIP_MEMORY_SCOPE_AGENT);
}
__device__ __forceinline__ void gstore(float* p, float v) {
  __hip_atomic_store(p, v, __ATOMIC_RELAXED, __HIP_MEMORY_SCOPE_AGENT);
}

__device__ __forceinline__ void atomicMaxFloat(float* p, float v) {
  int old = __float_as_int(*p);
  while (__int_as_float(old) < v) {
    int assumed = old;
    old = atomicCAS((int*)p, assumed, __float_as_int(v));
    if (old == assumed) break;
  }
}

// Fence-free grid barrier, grouped arrival (256 blocks = 8 groups x 32).
// Data-visibility model identical to round 3 (proven): all cross-block data
// moves via sc1 agent load/store or device atomics; __syncthreads + explicit
// s_waitcnt vmcnt(0) drains stores before arrival.
// Arrival: 32-way RMW per group counter (8 lines, 256B apart, in parallel).
// Group's last arriver stores done[g]=gen (plain sc1 store, no 2nd-level RMW).
// Block 0 polls the 8 read-only done flags, then fans out 8 release lines;
// all other blocks poll their group's release line. Counters monotonic.
// bar layout (uint idx, 64-uint spacing): gcnt[g]=g*64, done[g]=512+g*64,
// rel[g]=1024+g*64; total 1536 uints (6KB) inside legacy OFF_H region.
__device__ __forceinline__ void gbar(unsigned* bar, unsigned gen) {
  __syncthreads();                       // all waves' stores drained (vmcnt 0)
  if (threadIdx.x == 0) {
    asm volatile("s_waitcnt vmcnt(0)" ::: "memory");
    const unsigned g = blockIdx.x >> 5;
    unsigned prev = __hip_atomic_fetch_add(bar + g * 64, 1u,
                                           __ATOMIC_RELAXED, __HIP_MEMORY_SCOPE_AGENT);
    if (prev == gen * 32u - 1u)          // last arriver of this group
      __hip_atomic_store(bar + 512 + g * 64, gen,
                         __ATOMIC_RELAXED, __HIP_MEMORY_SCOPE_AGENT);
    unsigned spins = 0;
    if (blockIdx.x == 0) {
      for (;;) {                         // wait until all 8 groups done
        unsigned ok = 1;
        #pragma unroll
        for (int i = 0; i < 8; ++i)
          ok &= (__hip_atomic_load(bar + 512 + i * 64,
                                   __ATOMIC_RELAXED, __HIP_MEMORY_SCOPE_AGENT) >= gen);
        if (ok) break;
        __builtin_amdgcn_s_sleep(1);
        if (++spins > 400000u) break;    // fuse: fail loud, not hung
      }
      #pragma unroll
      for (int i = 0; i < 8; ++i)
        __hip_atomic_store(bar + 1024 + i * 64, gen,
                           __ATOMIC_RELAXED, __HIP_MEMORY_SCOPE_AGENT);
    } else {
      const unsigned* rel = bar + 1024 + g * 64;
      while (__hip_atomic_load(rel, __ATOMIC_RELAXED, __HIP_MEMORY_SCOPE_AGENT) < gen) {
        __builtin_amdgcn_s_sleep(1);
        if (++spins > 400000u) break;    // fuse
      }
    }
  }
  __syncthreads();
}

// ---------- one-time kernels ----------
__global__ void k_init(float* __restrict__ ws) {   // legacy state
  int i = blockIdx.x * blockDim.x + threadIdx.x;
  if (i < 3 * HB) { ws[OFF_H + i] = 0.f; ws[OFF_C + i] = 0.f; }
  if (i < KV * B) ws[OFF_CTX + i] = 0.f;
  if (i < B)      ws[OFF_Z + i] = 1.f;
}

__global__ void k_init2(float* __restrict__ ws) {  // new-path state
  int i = blockIdx.x * blockDim.x + threadIdx.x;
  if (i < 2048)    ws[OFF_H + i]    = 0.f;                    // barrier lines
  if (i < 4 * HB)  ws[NOFF_H01 + i] = 0.f;
  if (i < 3 * HB)  ws[NOFF_C + i]   = 0.f;
  if (i < HB)      ws[NOFF_H2 + i]  = 0.f;                    // h2 slot 0
  if (i < (long)(L + 1) * KVB) ws[NOFF_CTXA + i] = 0.f;       // atomic targets
  if (i < (L + 1) * B) ws[NOFF_ZA + i] = (i < B) ? 1.f : 0.f;
}

__global__ void k_embed(const int* __restrict__ labels, const float* __restrict__ emb,
                        float* __restrict__ xembT) {
  int i = blockIdx.x * blockDim.x + threadIdx.x;
  if (i >= L * E * B) return;
  int b = i & 63, e = (i >> 6) & 255, l = i >> 14;
  int lab = labels[l * B + b];
  xembT[i] = emb[lab * E + e];
}

__global__ void k_cvt(const float4* __restrict__ src, ushort4* __restrict__ dst, int n4) {
  int i = blockIdx.x * blockDim.x + threadIdx.x;
  int stride = gridDim.x * blockDim.x;
  for (int k = i; k < n4; k += stride) {
    float4 v = src[k];
    ushort4 o;
    o.x = f2bf(v.x); o.y = f2bf(v.y); o.z = f2bf(v.z); o.w = f2bf(v.w);
    dst[k] = o;
  }
}

// ---------- persistent fused decoder (plain launch + fence-free barrier) ----------
// grid 256 blocks x 512 threads; block bi owns gate column j = bi for all 3
// LSTM cells (weight rows staged in LDS once), and attention batch b = bi>>2
// with interleaved row segments. 4 gbar() per step.
__global__ __launch_bounds__(512, 1) void k_mega(
    const float* __restrict__ wih0, const float* __restrict__ whh0,
    const float* __restrict__ bih0, const float* __restrict__ bhh0,
    const float* __restrict__ wihr, const float* __restrict__ whhr,
    const float* __restrict__ bihr, const float* __restrict__ bhhr,
    const ushort* __restrict__ kbf, const ushort* __restrict__ vbf,
    const int* __restrict__ lens, const float* __restrict__ xe,
    float* __restrict__ h01, float* __restrict__ h2a,
    float* __restrict__ ctxa, float* __restrict__ za,
    unsigned* __restrict__ bar) {
  const int bi  = blockIdx.x;
  const int tid = threadIdx.x;
  const int b   = tid & 63;
  const int q   = (tid >> 6) & 3;
  const int ks  = tid >> 8;

  __shared__ float wA[4][768];   // cell0: [q][ wih row 512 | whh row 256 ]
  __shared__ float wB[4][512];   // cell1: [q][ wih 256 | whh 256 ]
  __shared__ float wC[4][512];   // cell2
  __shared__ float bs[3][4];
  __shared__ float red[2][4][64];
  __shared__ float4 asum[8][64];
  __shared__ float az[8];

  for (int i = tid; i < 4 * 768; i += 512) {
    int qq = i / 768, o = i - qq * 768;
    wA[qq][o] = (o < 512) ? wih0[(long)(qq * H + bi) * 512 + o]
                          : whh0[(long)(qq * H + bi) * 256 + (o - 512)];
  }
  for (int i = tid; i < 4 * 512; i += 512) {
    int qq = i >> 9, o = i & 511;
    long row = qq * H + bi;
    wB[qq][o] = (o < 256) ? wihr[row * H + o] : whhr[row * H + (o - 256)];
    wC[qq][o] = (o < 256) ? wihr[(long)G * H + row * H + o]
                          : whhr[(long)G * H + row * H + (o - 256)];
  }
  if (tid < 4) {
    bs[0][tid] = bih0[tid * H + bi] + bhh0[tid * H + bi];
    bs[1][tid] = bihr[tid * H + bi] + bhhr[tid * H + bi];
    bs[2][tid] = bihr[G + tid * H + bi] + bhhr[G + tid * H + bi];
  }
  __syncthreads();

  const int ab    = bi >> 2;                       // attention batch
  const int aseg  = ((bi & 3) << 3) + (tid >> 6);  // 0..31 interleave phase
  const int alane = tid & 63;
  const int alen  = lens[ab];

  float c0 = 0.f, c1 = 0.f, c2 = 0.f;              // cell state, threads tid<64

  for (int t = 0; t < L; ++t) {
    const int cur = t & 1, nxt = cur ^ 1;
    const float* h0p = h01 + (long)cur * 2 * HB;
    const float* h1p = h0p + HB;
    float* h0n = h01 + (long)nxt * 2 * HB;
    float* h1n = h0n + HB;
    const float* xet  = xe + (long)t * E * B;
    const float* ctxc = ctxa + (long)t * KVB;
    const float* h2p  = h2a + (long)t * HB;
    float* h2n        = h2a + (long)(t + 1) * HB;

    // ---------- layer 0 ----------
    {
      float acc;
      if (ks == 0) {
        float s0 = 0.f, s1 = 0.f, s2 = 0.f, s3 = 0.f;
        const float4* wi4 = (const float4*)wA[q];
        #pragma unroll 4
        for (int k = 0; k < 256; k += 4) {
          float4 w = wi4[k >> 2];
          s0 += w.x * xet[(k)     * B + b];
          s1 += w.y * xet[(k + 1) * B + b];
          s2 += w.z * xet[(k + 2) * B + b];
          s3 += w.w * xet[(k + 3) * B + b];
        }
        float a0 = 0.f, a1 = 0.f;
        const float4* wh4 = (const float4*)(wA[q] + 512);
        #pragma unroll 4
        for (int k = 0; k < 128; k += 4) {
          float4 w = wh4[k >> 2];
          a0 += w.x * gload(&h0p[(k)     * B + b]);
          a1 += w.y * gload(&h0p[(k + 1) * B + b]);
          a0 += w.z * gload(&h0p[(k + 2) * B + b]);
          a1 += w.w * gload(&h0p[(k + 3) * B + b]);
        }
        acc = bs[0][q] + (s0 + s1) + (s2 + s3) + (a0 + a1);
      } else {
        float zz = 1.f / fmaxf(gload(&za[t * B + b]), 1e-12f);
        float s0 = 0.f, s1 = 0.f, s2 = 0.f, s3 = 0.f;
        const float4* wi4 = (const float4*)(wA[q] + 256);
        #pragma unroll 4
        for (int k = 0; k < 256; k += 4) {
          float4 w = wi4[k >> 2];
          s0 += w.x * gload(&ctxc[(k)     * B + b]);
          s1 += w.y * gload(&ctxc[(k + 1) * B + b]);
          s2 += w.z * gload(&ctxc[(k + 2) * B + b]);
          s3 += w.w * gload(&ctxc[(k + 3) * B + b]);
        }
        float a0 = 0.f, a1 = 0.f;
        const float4* wh4 = (const float4*)(wA[q] + 640);
        #pragma unroll 4
        for (int k = 0; k < 128; k += 4) {
          float4 w = wh4[k >> 2];
          a0 += w.x * gload(&h0p[(128 + k) * B + b]);
          a1 += w.y * gload(&h0p[(129 + k) * B + b]);
          a0 += w.z * gload(&h0p[(130 + k) * B + b]);
          a1 += w.w * gload(&h0p[(131 + k) * B + b]);
        }
        acc = ((s0 + s1) + (s2 + s3)) * zz + (a0 + a1);
      }
      red[ks][q][b] = acc;
      __syncthreads();
      if (tid < 64) {
        float gi = red[0][0][tid] + red[1][0][tid];
        float gf = red[0][1][tid] + red[1][1][tid];
        float gg = red[0][2][tid] + red[1][2][tid];
        float go = red[0][3][tid] + red[1][3][tid];
        c0 = sigm(gf) * c0 + sigm(gi) * tanh_f(gg);
        gstore(&h0n[bi * B + tid], sigm(go) * tanh_f(c0));
      }
    }
    gbar(bar, 4 * t + 1);

    // ---------- layer 1 ----------
    {
      const int k0 = ks << 7;
      float a1 = 0.f, a2 = 0.f, a3 = 0.f, a4 = 0.f;
      const float4* wi4 = (const float4*)(wB[q] + k0);
      const float4* wh4 = (const float4*)(wB[q] + 256 + k0);
      #pragma unroll 4
      for (int k = 0; k < 128; k += 4) {
        float4 wi = wi4[k >> 2];
        float4 wh = wh4[k >> 2];
        a1 += wi.x * gload(&h0n[(k0 + k)     * B + b]);
        a2 += wi.y * gload(&h0n[(k0 + k + 1) * B + b]);
        a1 += wi.z * gload(&h0n[(k0 + k + 2) * B + b]);
        a2 += wi.w * gload(&h0n[(k0 + k + 3) * B + b]);
        a3 += wh.x * gload(&h1p[(k0 + k)     * B + b]);
        a4 += wh.y * gload(&h1p[(k0 + k + 1) * B + b]);
        a3 += wh.z * gload(&h1p[(k0 + k + 2) * B + b]);
        a4 += wh.w * gload(&h1p[(k0 + k + 3) * B + b]);
      }
      red[ks][q][b] = (ks ? 0.f : bs[1][q]) + (a1 + a2) + (a3 + a4);
      __syncthreads();
      if (tid < 64) {
        float gi = red[0][0][tid] + red[1][0][tid];
        float gf = red[0][1][tid] + red[1][1][tid];
        float gg = red[0][2][tid] + red[1][2][tid];
        float go = red[0][3][tid] + red[1][3][tid];
        c1 = sigm(gf) * c1 + sigm(gi) * tanh_f(gg);
        gstore(&h1n[bi * B + tid], sigm(go) * tanh_f(c1));
      }
    }
    gbar(bar, 4 * t + 2);

    // ---------- layer 2 ----------
    {
      const int k0 = ks << 7;
      float a1 = 0.f, a2 = 0.f, a3 = 0.f, a4 = 0.f;
      const float4* wi4 = (const float4*)(wC[q] + k0);
      const float4* wh4 = (const float4*)(wC[q] + 256 + k0);
      #pragma unroll 4
      for (int k = 0; k < 128; k += 4) {
        float4 wi = wi4[k >> 2];
        float4 wh = wh4[k >> 2];
        a1 += wi.x * gload(&h1n[(k0 + k)     * B + b]);
        a2 += wi.y * gload(&h1n[(k0 + k + 1) * B + b]);
        a1 += wi.z * gload(&h1n[(k0 + k + 2) * B + b]);
        a2 += wi.w * gload(&h1n[(k0 + k + 3) * B + b]);
        a3 += wh.x * gload(&h2p[(k0 + k)     * B + b]);
        a4 += wh.y * gload(&h2p[(k0 + k + 1) * B + b]);
        a3 += wh.z * gload(&h2p[(k0 + k + 2) * B + b]);
        a4 += wh.w * gload(&h2p[(k0 + k + 3) * B + b]);
      }
      red[ks][q][b] = (ks ? 0.f : bs[2][q]) + (a1 + a2) + (a3 + a4);
      __syncthreads();
      if (tid < 64) {
        float gi = red[0][0][tid] + red[1][0][tid];
        float gf = red[0][1][tid] + red[1][1][tid];
        float gg = red[0][2][tid] + red[1][2][tid];
        float go = red[0][3][tid] + red[1][3][tid];
        c2 = sigm(gf) * c2 + sigm(gi) * tanh_f(gg);
        gstore(&h2n[bi * B + tid], sigm(go) * tanh_f(c2));
      }
    }
    gbar(bar, 4 * t + 3);

    // ---------- attention (interleaved rows, unnormalized exp) ----------
    {
      float* ctxn = ctxa + (long)(t + 1) * KVB;
      float q0 = gload(&h2n[(4 * alane + 0) * B + ab]);
      float q1 = gload(&h2n[(4 * alane + 1) * B + ab]);
      float q2 = gload(&h2n[(4 * alane + 2) * B + ab]);
      float q3 = gload(&h2n[(4 * alane + 3) * B + ab]);
      float a0 = 0.f, a1 = 0.f, a2 = 0.f, a3 = 0.f, zp = 0.f;
      for (int r = aseg; r < alen; r += 32) {
        size_t off = ((size_t)(ab * T + r)) * KV + 4 * alane;
        uint2 kd = *(const uint2*)(kbf + off);
        uint2 vd = *(const uint2*)(vbf + off);
        float e = bf2f(kd.x & 0xffffu) * q0
                + __uint_as_float(kd.x & 0xffff0000u) * q1
                + bf2f(kd.y & 0xffffu) * q2
                + __uint_as_float(kd.y & 0xffff0000u) * q3;
        #pragma unroll
        for (int o = 32; o; o >>= 1) e += __shfl_xor(e, o, 64);
        float w = __expf(fminf(e, 50.f));
        a0 += w * bf2f(vd.x & 0xffffu);
        a1 += w * __uint_as_float(vd.x & 0xffff0000u);
        a2 += w * bf2f(vd.y & 0xffffu);
        a3 += w * __uint_as_float(vd.y & 0xffff0000u);
        zp += w;
      }
      int wv = tid >> 6;
      asum[wv][alane] = make_float4(a0, a1, a2, a3);
      if (alane == 0) az[wv] = zp;
      __syncthreads();
      if (tid < 256) {
        const float* as = (const float*)asum;
        float s = as[tid]        + as[256 + tid]  + as[512 + tid]  + as[768 + tid]
                + as[1024 + tid] + as[1280 + tid] + as[1536 + tid] + as[1792 + tid];
        atomicAdd(&ctxn[tid * B + ab], s);
      }
      if (tid == 0) {
        atomicAdd(&za[(t + 1) * B + ab],
                  az[0] + az[1] + az[2] + az[3] + az[4] + az[5] + az[6] + az[7]);
      }
    }
    gbar(bar, 4 * t + 4);
  }
}

// ---------- LSTM cells (legacy fallback) ----------
__global__ __launch_bounds__(512) void k_cell0(
    const float* __restrict__ wih, const float* __restrict__ whh,
    const float* __restrict__ bih, const float* __restrict__ bhh,
    const float* __restrict__ xe,
    const float* __restrict__ ctx, const float* __restrict__ Z,
    const float* __restrict__ hprev,
    float* __restrict__ hnew, float* __restrict__ cst) {
  int t = threadIdx.x;
  int b = t & 63, q = (t >> 6) & 3, ks = t >> 8;
  int j = blockIdx.x;
  int row = q * H + j;
  float acc = 0.f, s0 = 0.f, s1 = 0.f, s2 = 0.f, s3 = 0.f, a2 = 0.f;
  if (ks == 0) {
    acc = bih[row] + bhh[row];
    const float* wi = wih + (long)row * (E + KV);
    #pragma unroll 4
    for (int k = 0; k < E; k += 4) {
      s0 += wi[k]   * xe[(k)   * B + b];
      s1 += wi[k+1] * xe[(k+1) * B + b];
      s2 += wi[k+2] * xe[(k+2) * B + b];
      s3 += wi[k+3] * xe[(k+3) * B + b];
    }
    const float* wh = whh + (long)row * H;
    #pragma unroll 4
    for (int k = 0; k < 128; k += 2) {
      a2 += wh[k]   * hprev[(k)   * B + b];
      a2 += wh[k+1] * hprev[(k+1) * B + b];
    }
    acc += (s0 + s1) + (s2 + s3) + a2;
  } else {
    float zz = 1.f / fmaxf(Z[b], 1e-12f);
    const float* wi = wih + (long)row * (E + KV) + E;
    #pragma unroll 4
    for (int k = 0; k < KV; k += 4) {
      s0 += wi[k]   * ctx[(k)   * B + b];
      s1 += wi[k+1] * ctx[(k+1) * B + b];
      s2 += wi[k+2] * ctx[(k+2) * B + b];
      s3 += wi[k+3] * ctx[(k+3) * B + b];
    }
    const float* wh = whh + (long)row * H + 128;
    #pragma unroll 4
    for (int k = 0; k < 128; k += 2) {
      a2 += wh[k]   * hprev[(128 + k)     * B + b];
      a2 += wh[k+1] * hprev[(128 + k + 1) * B + b];
    }
    acc = ((s0 + s1) + (s2 + s3)) * zz + a2;
  }
  __shared__ float sh[2][4][64];
  sh[ks][q][b] = acc;
  __syncthreads();
  if (t < 64) {
    int bb = t;
    float gi = sh[0][0][bb] + sh[1][0][bb];
    float gf = sh[0][1][bb] + sh[1][1][bb];
    float gg = sh[0][2][bb] + sh[1][2][bb];
    float go = sh[0][3][bb] + sh[1][3][bb];
    float c = sigm(gf) * cst[j * B + bb] + sigm(gi) * tanh_f(gg);
    float h = sigm(go) * tanh_f(c);
    cst[j * B + bb] = c;
    hnew[j * B + bb] = h;
  }
}

__global__ __launch_bounds__(512) void k_cellr(
    const float* __restrict__ wih, const float* __restrict__ whh,
    const float* __restrict__ bih, const float* __restrict__ bhh,
    const float* __restrict__ hin, const float* __restrict__ hprevL,
    float* __restrict__ hnewL, float* __restrict__ cst,
    float* __restrict__ ctxn, float* __restrict__ Zn, float* __restrict__ m, int aux) {
  int t = threadIdx.x;
  int b = t & 63, q = (t >> 6) & 3, ks = t >> 8;
  int j = blockIdx.x;
  int row = q * H + j;
  if (aux) {
    int gid = blockIdx.x * 512 + t;
    if (gid < KV * B) ctxn[gid] = 0.f;
    if (gid < B) { Zn[gid] = 0.f; m[gid] = -3.4e38f; }
  }
  float acc = ks ? 0.f : (bih[row] + bhh[row]);
  float a1 = 0.f, a2 = 0.f, a3 = 0.f, a4 = 0.f;
  const float* wi = wih + (long)row * H + ks * 128;
  const float* wh = whh + (long)row * H + ks * 128;
  int k0 = ks * 128;
  #pragma unroll 4
  for (int k = 0; k < 128; k += 2) {
    a1 += wi[k]   * hin[(k0 + k)     * B + b];
    a2 += wi[k+1] * hin[(k0 + k + 1) * B + b];
    a3 += wh[k]   * hprevL[(k0 + k)     * B + b];
    a4 += wh[k+1] * hprevL[(k0 + k + 1) * B + b];
  }
  acc += (a1 + a2) + (a3 + a4);
  __shared__ float sh[2][4][64];
  sh[ks][q][b] = acc;
  __syncthreads();
  if (t < 64) {
    int bb = t;
    float gi = sh[0][0][bb] + sh[1][0][bb];
    float gf = sh[0][1][bb] + sh[1][1][bb];
    float gg = sh[0][2][bb] + sh[1][2][bb];
    float go = sh[0][3][bb] + sh[1][3][bb];
    float c = sigm(gf) * cst[j * B + bb] + sigm(gi) * tanh_f(gg);
    float h = sigm(go) * tanh_f(c);
    cst[j * B + bb] = c;
    hnewL[j * B + bb] = h;
  }
}

// ---------- deferred MLP head (new path) ----------
__global__ __launch_bounds__(256) void k_fc1c(
    const float* __restrict__ w, const float* __restrict__ bias,
    const float* __restrict__ h2a, const float* __restrict__ ctxa,
    const float* __restrict__ za, float* __restrict__ hidc, int t0) {
  int s = blockIdx.y;
  int t = t0 + s;
  const float* h2  = h2a  + (long)(t + 1) * HB;
  const float* ctx = ctxa + (long)(t + 1) * KVB;
  int tid = threadIdx.x;
  int b = tid & 63, jl = tid >> 6;
  int j = blockIdx.x * 4 + jl;
  float zz = 1.f / fmaxf(za[(t + 1) * B + b], 1e-12f);
  const float* wr = w + (long)j * (H + KV);
  float s0 = 0.f, s1 = 0.f, c0 = 0.f, c1 = 0.f;
  #pragma unroll 4
  for (int k = 0; k < 256; k += 2) {
    s0 += wr[k]       * h2[(k)   * B + b];
    s1 += wr[k+1]     * h2[(k+1) * B + b];
    c0 += wr[256 + k]   * ctx[(k)   * B + b];
    c1 += wr[256 + k+1] * ctx[(k+1) * B + b];
  }
  float acc = bias[j] + (s0 + s1) + (c0 + c1) * zz;
  hidc[((long)s * MH + j) * B + b] = fmaxf(acc, 0.f);
}

__global__ __launch_bounds__(64) void k_fc2c(
    const float* __restrict__ w, const float* __restrict__ bias,
    const float* __restrict__ hidc, float* __restrict__ out, int t0) {
  int s = blockIdx.y;
  int v = blockIdx.x;
  int b = threadIdx.x;
  const float* hid = hidc + (long)s * MH * B;
  const float* wr = w + (long)v * MH;
  float s0 = 0.f, s1 = 0.f, s2 = 0.f, s3 = 0.f;
  #pragma unroll 4
  for (int k = 0; k < MH; k += 4) {
    s0 += wr[k]   * hid[(k)   * B + b];
    s1 += wr[k+1] * hid[(k+1) * B + b];
    s2 += wr[k+2] * hid[(k+2) * B + b];
    s3 += wr[k+3] * hid[(k+3) * B + b];
  }
  out[((long)b * L + (t0 + s)) * V + v] = bias[v] + (s0 + s1) + (s2 + s3);
}

// ---------- legacy fallback extras ----------
template <int BF>
__global__ __launch_bounds__(256) void k_energy(
    const void* __restrict__ keyp, const float* __restrict__ h2,
    const int* __restrict__ lens, float* __restrict__ e, float* __restrict__ m) {
  int b = blockIdx.y;
  int len = lens[b];
  int wave = threadIdx.x >> 6, lane = threadIdx.x & 63;
  int t0 = (blockIdx.x * 4 + wave) * 16;
  if (t0 >= len) return;
  float h0 = h2[(4 * lane + 0) * B + b];
  float h1 = h2[(4 * lane + 1) * B + b];
  float h2v = h2[(4 * lane + 2) * B + b];
  float h3 = h2[(4 * lane + 3) * B + b];
  int tend = min(t0 + 16, len);
  float wmax = -3.4e38f;
  for (int t = t0; t < tend; t++) {
    float4 kv;
    if (BF) {
      const uint2* p = (const uint2*)((const ushort*)keyp + (size_t)(b * T + t) * KV + 4 * lane);
      uint2 d = *p;
      kv.x = bf2f(d.x & 0xffffu);
      kv.y = __uint_as_float(d.x & 0xffff0000u);
      kv.z = bf2f(d.y & 0xffffu);
      kv.w = __uint_as_float(d.y & 0xffff0000u);
    } else {
      kv = ((const float4*)((const float*)keyp + (size_t)(b * T + t) * KV))[lane];
    }
    float s = kv.x * h0 + kv.y * h1 + kv.z * h2v + kv.w * h3;
    #pragma unroll
    for (int off = 32; off; off >>= 1) s += __shfl_xor(s, off, 64);
    if (lane == 0) e[b * T + t] = s;
    wmax = fmaxf(wmax, s);
  }
  if (lane == 0) atomicMaxFloat(&m[b], wmax);
}

template <int BF>
__global__ __launch_bounds__(256) void k_pv(
    const void* __restrict__ valp, const float* __restrict__ e, const float* __restrict__ m,
    const int* __restrict__ lens, float* __restrict__ ctxn, float* __restrict__ Zn) {
  int b = blockIdx.y;
  int len = lens[b];
  int t0blk = blockIdx.x * 256;
  if (t0blk >= len) return;
  int wave = threadIdx.x >> 6, lane = threadIdx.x & 63;
  float mb = m[b];
  float a0 = 0.f, a1 = 0.f, a2 = 0.f, a3 = 0.f, zp = 0.f;
  int t0 = t0blk + wave * 64;
  int tend = min(t0 + 64, len);
  for (int t = t0; t < tend; t++) {
    float w = __expf(e[b * T + t] - mb);
    float4 vv;
    if (BF) {
      const uint2* p = (const uint2*)((const ushort*)valp + (size_t)(b * T + t) * KV + 4 * lane);
      uint2 d = *p;
      vv.x = bf2f(d.x & 0xffffu);
      vv.y = __uint_as_float(d.x & 0xffff0000u);
      vv.z = bf2f(d.y & 0xffffu);
      vv.w = __uint_as_float(d.y & 0xffff0000u);
    } else {
      vv = ((const float4*)((const float*)valp + (size_t)(b * T + t) * KV))[lane];
    }
    a0 += w * vv.x; a1 += w * vv.y; a2 += w * vv.z; a3 += w * vv.w;
    zp += w;
  }
  __shared__ float sh[4][256];
  __shared__ float shz[4];
  sh[wave][4 * lane + 0] = a0;
  sh[wave][4 * lane + 1] = a1;
  sh[wave][4 * lane + 2] = a2;
  sh[wave][4 * lane + 3] = a3;
  if (lane == 0) shz[wave] = zp;
  __syncthreads();
  if (wave == 0) {
    #pragma unroll
    for (int r = 0; r < 4; r++) {
      int d = lane * 4 + r;
      float s = sh[0][d] + sh[1][d] + sh[2][d] + sh[3][d];
      atomicAdd(&ctxn[d * B + b], s);
    }
    if (lane == 0) atomicAdd(&Zn[b], shz[0] + shz[1] + shz[2] + shz[3]);
  }
}

__global__ __launch_bounds__(256) void k_fc1(
    const float* __restrict__ w, const float* __restrict__ bias,
    const float* __restrict__ h2, const float* __restrict__ ctxn, const float* __restrict__ Zn,
    float* __restrict__ hid) {
  int t = threadIdx.x;
  int b = t & 63, jl = t >> 6;
  int j = blockIdx.x * 4 + jl;
  float zz = 1.f / fmaxf(Zn[b], 1e-12f);
  const float* wr = w + (long)j * (H + KV);
  float s0 = 0.f, s1 = 0.f, s2 = 0.f, s3 = 0.f, a2 = 0.f, a3 = 0.f;
  #pragma unroll 4
  for (int k = 0; k < H; k += 4) {
    s0 += wr[k]   * h2[(k)   * B + b];
    s1 += wr[k+1] * h2[(k+1) * B + b];
    s2 += wr[k+2] * h2[(k+2) * B + b];
    s3 += wr[k+3] * h2[(k+3) * B + b];
  }
  #pragma unroll 4
  for (int k = 0; k < KV; k += 2) {
    a2 += wr[H + k]     * ctxn[(k)   * B + b];
    a3 += wr[H + k + 1] * ctxn[(k+1) * B + b];
  }
  float acc = bias[j] + (s0 + s1) + (s2 + s3) + (a2 + a3) * zz;
  hid[j * B + b] = fmaxf(acc, 0.f);
}

__global__ __launch_bounds__(64) void k_fc2(
    const float* __restrict__ w, const float* __restrict__ bias,
    const float* __restrict__ hid, float* __restrict__ out, int step) {
  int b = threadIdx.x;
  int v = blockIdx.x;
  const float* wr = w + (long)v * MH;
  float s0 = 0.f, s1 = 0.f, s2 = 0.f, s3 = 0.f;
  #pragma unroll 4
  for (int k = 0; k < MH; k += 4) {
    s0 += wr[k]   * hid[(k)   * B + b];
    s1 += wr[k+1] * hid[(k+1) * B + b];
    s2 += wr[k+2] * hid[(k+2) * B + b];
    s3 += wr[k+3] * hid[(k+3) * B + b];
  }
  out[((long)b * L + step) * V + v] = bias[v] + (s0 + s1) + (s2 + s3);
}

static void launch_legacy(const float* key, const float* value, const int* lens,
                          const float* w_ih0, const float* w_hh0,
                          const float* b_ih0, const float* b_hh0,
                          const float* w_ihr, const float* w_hhr,
                          const float* b_ihr, const float* b_hhr,
                          const float* fc1_w, const float* fc1_b,
                          const float* fc2_w, const float* fc2_b,
                          float* out, float* ws,
                          const ushort* kbf, const ushort* vbf, bool bf,
                          hipStream_t stream) {
  float* hbuf = ws + OFF_H;
  float* cbuf = ws + OFF_C;
  float* ctxb = ws + OFF_CTX;
  float* Zb   = ws + OFF_Z;
  float* mb   = ws + OFF_M;
  float* eb   = ws + OFF_E;
  float* hid  = ws + OFF_HID;
  float* xe   = ws + OFF_XE;
  for (int t = 0; t < L; t++) {
    int cur = t & 1, nxt = cur ^ 1;
    float* hprev = hbuf + (long)cur * 3 * HB;
    float* hnew  = hbuf + (long)nxt * 3 * HB;
    float* ctxc  = ctxb + (long)cur * KV * B;
    float* ctxn  = ctxb + (long)nxt * KV * B;
    float* Zc = Zb + cur * B;
    float* Zn = Zb + nxt * B;

    k_cell0<<<H, 512, 0, stream>>>(w_ih0, w_hh0, b_ih0, b_hh0,
                                   xe + (long)t * E * B, ctxc, Zc,
                                   hprev, hnew, cbuf);
    k_cellr<<<H, 512, 0, stream>>>(w_ihr, w_hhr, b_ihr, b_hhr,
                                   hnew, hprev + HB, hnew + HB, cbuf + HB,
                                   ctxn, Zn, mb, 1);
    k_cellr<<<H, 512, 0, stream>>>(w_ihr + (long)G * H, w_hhr + (long)G * H,
                                   b_ihr + G, b_hhr + G,
                                   hnew + HB, hprev + 2 * HB, hnew + 2 * HB, cbuf + 2 * HB,
                                   nullptr, nullptr, nullptr, 0);
    if (bf) {
      k_energy<1><<<dim3(T / 64, B), 256, 0, stream>>>(kbf, hnew + 2 * HB, lens, eb, mb);
      k_pv<1><<<dim3(T / 256, B), 256, 0, stream>>>(vbf, eb, mb, lens, ctxn, Zn);
    } else {
      k_energy<0><<<dim3(T / 64, B), 256, 0, stream>>>(key, hnew + 2 * HB, lens, eb, mb);
      k_pv<0><<<dim3(T / 256, B), 256, 0, stream>>>(value, eb, mb, lens, ctxn, Zn);
    }
    k_fc1<<<MH / 4, 256, 0, stream>>>(fc1_w, fc1_b, hnew + 2 * HB, ctxn, Zn, hid);
    k_fc2<<<V, 64, 0, stream>>>(fc2_w, fc2_b, hid, out, t);
  }
}

extern "C" void kernel_launch(void* const* d_in, const int* in_sizes, int n_in,
                              void* d_out, int out_size, void* d_ws, size_t ws_size,
                              hipStream_t stream) {
  const float* key    = (const float*)d_in[0];
  const float* value  = (const float*)d_in[1];
  const int*   labels = (const int*)d_in[2];
  const int*   lens   = (const int*)d_in[3];
  const float* emb    = (const float*)d_in[4];
  const float* w_ih0  = (const float*)d_in[5];
  const float* w_hh0  = (const float*)d_in[6];
  const float* b_ih0  = (const float*)d_in[7];
  const float* b_hh0  = (const float*)d_in[8];
  const float* w_ihr  = (const float*)d_in[9];
  const float* w_hhr  = (const float*)d_in[10];
  const float* b_ihr  = (const float*)d_in[11];
  const float* b_hhr  = (const float*)d_in[12];
  const float* fc1_w  = (const float*)d_in[13];
  const float* fc1_b  = (const float*)d_in[14];
  const float* fc2_w  = (const float*)d_in[15];
  const float* fc2_b  = (const float*)d_in[16];
  float* out = (float*)d_out;
  float* ws  = (float*)d_ws;

  bool bf      = ((long)ws_size >= NEED_BF);
  bool newpath = ((long)ws_size >= NEED_NEW);
  ushort* kbf = (ushort*)((char*)d_ws + FLOATBYTES);
  ushort* vbf = kbf + KVELEMS;

  k_embed<<<(L * E * B + 255) / 256, 256, 0, stream>>>(labels, emb, ws + OFF_XE);
  if (bf) {
    int n4 = (int)(KVELEMS >> 2);
    k_cvt<<<4096, 256, 0, stream>>>((const float4*)key, (ushort4*)kbf, n4);
    k_cvt<<<4096, 256, 0, stream>>>((const float4*)value, (ushort4*)vbf, n4);
  }

  if (newpath) {
    k_init2<<<(int)(((long)(L + 1) * KVB + 255) / 256), 256, 0, stream>>>(ws);
    float* h01  = ws + NOFF_H01;
    float* h2a  = ws + NOFF_H2;
    float* ctxa = ws + NOFF_CTXA;
    float* za   = ws + NOFF_ZA;
    float* hidc = ws + NOFF_HIDC;
    float* xep  = ws + OFF_XE;
    unsigned* bar = (unsigned*)(ws + OFF_H);

    k_mega<<<256, 512, 0, stream>>>(w_ih0, w_hh0, b_ih0, b_hh0,
                                    w_ihr, w_hhr, b_ihr, b_hhr,
                                    kbf, vbf, lens, xep,
                                    h01, h2a, ctxa, za, bar);

    for (int c = 0; c < L / CS; c++) {
      int t0 = c * CS;
      k_fc1c<<<dim3(MH / 4, CS), 256, 0, stream>>>(fc1_w, fc1_b, h2a, ctxa, za, hidc, t0);
      k_fc2c<<<dim3(V, CS), 64, 0, stream>>>(fc2_w, fc2_b, hidc, out, t0);
    }
  } else {
    k_init<<<(3 * HB + 255) / 256, 256, 0, stream>>>(ws);
    launch_legacy(key, value, lens, w_ih0, w_hh0, b_ih0, b_hh0,
                  w_ihr, w_hhr, b_ihr, b_hhr, fc1_w, fc1_b, fc2_w, fc2_b,
                  out, ws, kbf, vbf, bf, stream);
  }
}

// Round 6
// 14403.769 us; speedup vs baseline: 4.7510x; 1.0055x over previous
//
#include <hip/hip_runtime.h>
#include <hip/hip_bf16.h>

namespace {
constexpr int B  = 64;
constexpr int T  = 2048;
constexpr int L  = 200;
constexpr int H  = 256;
constexpr int KV = 256;
constexpr int E  = 256;
constexpr int V  = 33;
constexpr int MH = 512;
constexpr int G  = 4 * H;
constexpr int HB = H * B;       // 16384
constexpr int KVB = KV * B;     // 16384
constexpr int CS = 50;          // head chunk (steps)

// ---- legacy (round-0) float layout ----
constexpr long OFF_H   = 0;                        // legacy h dbuf; newpath reuses [0..2047] as barrier
constexpr long OFF_C   = OFF_H  + 2L * 3 * HB;
constexpr long OFF_CTX = OFF_C  + 3L * HB;         // ctx double buffer [2][KV][B]
constexpr long OFF_Z   = OFF_CTX + 2L * KV * B;
constexpr long OFF_M   = OFF_Z  + 2L * B;
constexpr long OFF_E   = OFF_M  + B;
constexpr long OFF_HID = OFF_E  + (long)B * T;
constexpr long OFF_XE  = OFF_HID + (long)MH * B;   // xembT [L][E][B] (both paths)
constexpr long FLOATS_OLD = OFF_XE + (long)L * E * B;
constexpr long FLOATBYTES = FLOATS_OLD * 4;
constexpr long KVELEMS = (long)B * T * KV;         // 33,554,432
constexpr long NEED_BF = FLOATBYTES + 2 * KVELEMS * 2;   // legacy + bf16 KV

// ---- new-path extra region (after bf16 KV) ----
constexpr long NOFF      = NEED_BF / 4;            // float offset (16B aligned)
constexpr long NOFF_H01  = NOFF;                   // [2][2][H][B] layers 0,1 ping-pong
constexpr long NOFF_C    = NOFF_H01 + 4L * HB;     // [3][H][B]
constexpr long NOFF_H2   = NOFF_C   + 3L * HB;     // [L+1][H][B]
constexpr long NOFF_CTXA = NOFF_H2  + (long)(L + 1) * HB;   // [L+1][KV][B]
constexpr long NOFF_ZA   = NOFF_CTXA + (long)(L + 1) * KVB; // [L+1][B]
constexpr long NOFF_HIDC = NOFF_ZA  + (long)(L + 1) * B;    // [CS][MH][B]
constexpr long FLOATS_NEW = NOFF_HIDC + (long)CS * MH * B;
constexpr long NEED_NEW   = FLOATS_NEW * 4;        // ~182.1 MB
}

__device__ __forceinline__ float sigm(float x) { return 1.f / (1.f + __expf(-x)); }
__device__ __forceinline__ float tanh_f(float x) {
  float xc = fminf(fmaxf(x, -15.f), 15.f);
  float e2 = __expf(2.f * xc);
  return (e2 - 1.f) / (e2 + 1.f);
}
__device__ __forceinline__ ushort f2bf(float x) {
  unsigned u = __float_as_uint(x);
  unsigned r = (u + 0x7fffu + ((u >> 16) & 1u)) >> 16;
  return (ushort)r;
}
__device__ __forceinline__ float bf2f(unsigned v) { return __uint_as_float(v << 16); }

// device-coherent (L2-bypassing, sc1) scalar load/store for cross-block state.
__device__ __forceinline__ float gload(const float* p) {
  return __hip_atomic_load(p, __ATOMIC_RELAXED, __HIP_MEMORY_SCOPE_AGENT);
}
__device__ __forceinline__ void gstore(float* p, float v) {
  __hip_atomic_store(p, v, __ATOMIC_RELAXED, __HIP_MEMORY_SCOPE_AGENT);
}

__device__ __forceinline__ void atomicMaxFloat(float* p, float v) {
  int old = __float_as_int(*p);
  while (__int_as_float(old) < v) {
    int assumed = old;
    old = atomicCAS((int*)p, assumed, __float_as_int(v));
    if (old == assumed) break;
  }
}

// Stage a 64KB [256][64] f32 array from global (device-coherent sc1 path,
// bypassing the non-coherent per-XCD L2) into LDS. 512 threads x 8 float4,
// fully coalesced. Loads issued as 8 independent dwordx4 (sc0 sc1), one
// vmcnt(0) drain, then LDS writes. Outputs unused until after the waitcnt;
// register liveness keeps inputs/outputs disjoint.
__device__ __forceinline__ void stage64(const float* __restrict__ g,
                                        float* __restrict__ lds, int tid) {
  const float4* s = (const float4*)g;
  const float4* p0 = s + tid;
  const float4* p1 = s + tid + 512;
  const float4* p2 = s + tid + 1024;
  const float4* p3 = s + tid + 1536;
  const float4* p4 = s + tid + 2048;
  const float4* p5 = s + tid + 2560;
  const float4* p6 = s + tid + 3072;
  const float4* p7 = s + tid + 3584;
  float4 r0, r1, r2, r3, r4, r5, r6, r7;
  asm volatile("global_load_dwordx4 %0, %1, off sc0 sc1" : "=v"(r0) : "v"(p0));
  asm volatile("global_load_dwordx4 %0, %1, off sc0 sc1" : "=v"(r1) : "v"(p1));
  asm volatile("global_load_dwordx4 %0, %1, off sc0 sc1" : "=v"(r2) : "v"(p2));
  asm volatile("global_load_dwordx4 %0, %1, off sc0 sc1" : "=v"(r3) : "v"(p3));
  asm volatile("global_load_dwordx4 %0, %1, off sc0 sc1" : "=v"(r4) : "v"(p4));
  asm volatile("global_load_dwordx4 %0, %1, off sc0 sc1" : "=v"(r5) : "v"(p5));
  asm volatile("global_load_dwordx4 %0, %1, off sc0 sc1" : "=v"(r6) : "v"(p6));
  asm volatile("global_load_dwordx4 %0, %1, off sc0 sc1" : "=v"(r7) : "v"(p7));
  asm volatile("s_waitcnt vmcnt(0)" ::: "memory");
  float4* d = (float4*)lds;
  d[tid]        = r0;
  d[tid + 512]  = r1;
  d[tid + 1024] = r2;
  d[tid + 1536] = r3;
  d[tid + 2048] = r4;
  d[tid + 2560] = r5;
  d[tid + 3072] = r6;
  d[tid + 3584] = r7;
}

// Fence-free grid barrier, grouped arrival (256 blocks = 8 groups x 32).
// Proven in round 5. bar layout (uint idx, 64-uint spacing): gcnt[g]=g*64,
// done[g]=512+g*64, rel[g]=1024+g*64.
__device__ __forceinline__ void gbar(unsigned* bar, unsigned gen) {
  __syncthreads();                       // all waves' stores drained (vmcnt 0)
  if (threadIdx.x == 0) {
    asm volatile("s_waitcnt vmcnt(0)" ::: "memory");
    const unsigned g = blockIdx.x >> 5;
    unsigned prev = __hip_atomic_fetch_add(bar + g * 64, 1u,
                                           __ATOMIC_RELAXED, __HIP_MEMORY_SCOPE_AGENT);
    if (prev == gen * 32u - 1u)          // last arriver of this group
      __hip_atomic_store(bar + 512 + g * 64, gen,
                         __ATOMIC_RELAXED, __HIP_MEMORY_SCOPE_AGENT);
    unsigned spins = 0;
    if (blockIdx.x == 0) {
      for (;;) {                         // wait until all 8 groups done
        unsigned ok = 1;
        #pragma unroll
        for (int i = 0; i < 8; ++i)
          ok &= (__hip_atomic_load(bar + 512 + i * 64,
                                   __ATOMIC_RELAXED, __HIP_MEMORY_SCOPE_AGENT) >= gen);
        if (ok) break;
        __builtin_amdgcn_s_sleep(1);
        if (++spins > 400000u) break;    // fuse: fail loud, not hung
      }
      #pragma unroll
      for (int i = 0; i < 8; ++i)
        __hip_atomic_store(bar + 1024 + i * 64, gen,
                           __ATOMIC_RELAXED, __HIP_MEMORY_SCOPE_AGENT);
    } else {
      const unsigned* rel = bar + 1024 + g * 64;
      while (__hip_atomic_load(rel, __ATOMIC_RELAXED, __HIP_MEMORY_SCOPE_AGENT) < gen) {
        __builtin_amdgcn_s_sleep(1);
        if (++spins > 400000u) break;    // fuse
      }
    }
  }
  __syncthreads();
}

// ---------- one-time kernels ----------
__global__ void k_init(float* __restrict__ ws) {   // legacy state
  int i = blockIdx.x * blockDim.x + threadIdx.x;
  if (i < 3 * HB) { ws[OFF_H + i] = 0.f; ws[OFF_C + i] = 0.f; }
  if (i < KV * B) ws[OFF_CTX + i] = 0.f;
  if (i < B)      ws[OFF_Z + i] = 1.f;
}

// new-path state init: ALL writes sc1 (bypass L2) so no dirty zero-lines can
// linger in any XCD's L2 and later evict over atomically-produced values.
__global__ void k_init2(float* __restrict__ ws) {
  long i = (long)blockIdx.x * blockDim.x + threadIdx.x;
  if (i < 2048)    gstore(&ws[OFF_H + i], 0.f);               // barrier lines
  if (i < 4 * HB)  gstore(&ws[NOFF_H01 + i], 0.f);
  if (i < 3 * HB)  gstore(&ws[NOFF_C + i], 0.f);
  if (i < HB)      gstore(&ws[NOFF_H2 + i], 0.f);             // h2 slot 0
  if (i < (long)(L + 1) * KVB) gstore(&ws[NOFF_CTXA + i], 0.f);
  if (i < (L + 1) * B) gstore(&ws[NOFF_ZA + i], (i < B) ? 1.f : 0.f);
}

__global__ void k_embed(const int* __restrict__ labels, const float* __restrict__ emb,
                        float* __restrict__ xembT) {
  int i = blockIdx.x * blockDim.x + threadIdx.x;
  if (i >= L * E * B) return;
  int b = i & 63, e = (i >> 6) & 255, l = i >> 14;
  int lab = labels[l * B + b];
  xembT[i] = emb[lab * E + e];
}

__global__ void k_cvt(const float4* __restrict__ src, ushort4* __restrict__ dst, int n4) {
  int i = blockIdx.x * blockDim.x + threadIdx.x;
  int stride = gridDim.x * blockDim.x;
  for (int k = i; k < n4; k += stride) {
    float4 v = src[k];
    ushort4 o;
    o.x = f2bf(v.x); o.y = f2bf(v.y); o.z = f2bf(v.z); o.w = f2bf(v.w);
    dst[k] = o;
  }
}

// ---------- persistent fused decoder ----------
// grid 256 blocks x 512 threads; block bi owns gate column j = bi for all 3
// LSTM cells (weights in LDS once). Per-layer input vectors (64KB [256][64])
// are LDS-staged via coalesced sc1 dwordx4 (stage64), killing the 4x gate
// redundancy of scattered scalar sc1 loads. 4 gbar() per step.
__global__ __launch_bounds__(512, 1) void k_mega(
    const float* __restrict__ wih0, const float* __restrict__ whh0,
    const float* __restrict__ bih0, const float* __restrict__ bhh0,
    const float* __restrict__ wihr, const float* __restrict__ whhr,
    const float* __restrict__ bihr, const float* __restrict__ bhhr,
    const ushort* __restrict__ kbf, const ushort* __restrict__ vbf,
    const int* __restrict__ lens, const float* __restrict__ xe,
    float* __restrict__ h01, float* __restrict__ h2a,
    float* __restrict__ ctxa, float* __restrict__ za,
    unsigned* __restrict__ bar) {
  const int bi  = blockIdx.x;
  const int tid = threadIdx.x;
  const int b   = tid & 63;
  const int q   = (tid >> 6) & 3;
  const int ks  = tid >> 8;

  __shared__ float wA[4][768];   // cell0: [q][ wih row 512 | whh row 256 ]
  __shared__ float wB[4][512];   // cell1: [q][ wih 256 | whh 256 ]
  __shared__ float wC[4][512];   // cell2
  __shared__ float bs[3][4];
  __shared__ float red[2][4][64];
  __shared__ float4 asum[8][64];
  __shared__ float az[8];
  __shared__ float st[16384];    // 64KB staged input vector [256][64]

  for (int i = tid; i < 4 * 768; i += 512) {
    int qq = i / 768, o = i - qq * 768;
    wA[qq][o] = (o < 512) ? wih0[(long)(qq * H + bi) * 512 + o]
                          : whh0[(long)(qq * H + bi) * 256 + (o - 512)];
  }
  for (int i = tid; i < 4 * 512; i += 512) {
    int qq = i >> 9, o = i & 511;
    long row = qq * H + bi;
    wB[qq][o] = (o < 256) ? wihr[row * H + o] : whhr[row * H + (o - 256)];
    wC[qq][o] = (o < 256) ? wihr[(long)G * H + row * H + o]
                          : whhr[(long)G * H + row * H + (o - 256)];
  }
  if (tid < 4) {
    bs[0][tid] = bih0[tid * H + bi] + bhh0[tid * H + bi];
    bs[1][tid] = bihr[tid * H + bi] + bhhr[tid * H + bi];
    bs[2][tid] = bihr[G + tid * H + bi] + bhhr[G + tid * H + bi];
  }
  __syncthreads();

  const int ab    = bi >> 2;                       // attention batch
  const int aseg  = ((bi & 3) << 3) + (tid >> 6);  // 0..31 interleave phase
  const int alane = tid & 63;
  const int alen  = lens[ab];

  float c0 = 0.f, c1 = 0.f, c2 = 0.f;              // cell state, threads tid<64

  for (int t = 0; t < L; ++t) {
    const int cur = t & 1, nxt = cur ^ 1;
    const float* h0p = h01 + (long)cur * 2 * HB;
    const float* h1p = h0p + HB;
    float* h0n = h01 + (long)nxt * 2 * HB;
    float* h1n = h0n + HB;
    const float* xet  = xe + (long)t * E * B;
    const float* ctxc = ctxa + (long)t * KVB;
    const float* h2p  = h2a + (long)t * HB;
    float* h2n        = h2a + (long)(t + 1) * HB;

    // ---------- layer 0 ----------
    {
      stage64(ctxc, st, tid);
      __syncthreads();
      float sdot;
      if (ks == 0) {
        float s0 = 0.f, s1 = 0.f, s2 = 0.f, s3 = 0.f;
        const float4* wi4 = (const float4*)wA[q];
        #pragma unroll 4
        for (int k = 0; k < 256; k += 4) {
          float4 w = wi4[k >> 2];
          s0 += w.x * xet[(k)     * B + b];
          s1 += w.y * xet[(k + 1) * B + b];
          s2 += w.z * xet[(k + 2) * B + b];
          s3 += w.w * xet[(k + 3) * B + b];
        }
        sdot = (s0 + s1) + (s2 + s3);
      } else {
        float zz = 1.f / fmaxf(gload(&za[t * B + b]), 1e-12f);
        float s0 = 0.f, s1 = 0.f, s2 = 0.f, s3 = 0.f;
        const float4* wi4 = (const float4*)(wA[q] + 256);
        #pragma unroll 8
        for (int k = 0; k < 256; k += 4) {
          float4 w = wi4[k >> 2];
          s0 += w.x * st[(k)     * 64 + b];
          s1 += w.y * st[(k + 1) * 64 + b];
          s2 += w.z * st[(k + 2) * 64 + b];
          s3 += w.w * st[(k + 3) * 64 + b];
        }
        sdot = ((s0 + s1) + (s2 + s3)) * zz;
      }
      __syncthreads();
      stage64(h0p, st, tid);
      __syncthreads();
      {
        const int kh = ks << 7;
        float a0 = 0.f, a1 = 0.f;
        const float4* wh4 = (const float4*)(wA[q] + 512 + kh);
        #pragma unroll 8
        for (int k = 0; k < 128; k += 4) {
          float4 w = wh4[k >> 2];
          a0 += w.x * st[(kh + k)     * 64 + b];
          a1 += w.y * st[(kh + k + 1) * 64 + b];
          a0 += w.z * st[(kh + k + 2) * 64 + b];
          a1 += w.w * st[(kh + k + 3) * 64 + b];
        }
        red[ks][q][b] = (ks ? 0.f : bs[0][q]) + sdot + (a0 + a1);
      }
      __syncthreads();
      if (tid < 64) {
        float gi = red[0][0][tid] + red[1][0][tid];
        float gf = red[0][1][tid] + red[1][1][tid];
        float gg = red[0][2][tid] + red[1][2][tid];
        float go = red[0][3][tid] + red[1][3][tid];
        c0 = sigm(gf) * c0 + sigm(gi) * tanh_f(gg);
        gstore(&h0n[bi * B + tid], sigm(go) * tanh_f(c0));
      }
    }
    gbar(bar, 4 * t + 1);

    // ---------- layer 1 ----------
    {
      stage64(h0n, st, tid);
      __syncthreads();
      const int k0 = ks << 7;
      float a1 = 0.f, a2 = 0.f;
      {
        const float4* wi4 = (const float4*)(wB[q] + k0);
        #pragma unroll 8
        for (int k = 0; k < 128; k += 4) {
          float4 wi = wi4[k >> 2];
          a1 += wi.x * st[(k0 + k)     * 64 + b];
          a2 += wi.y * st[(k0 + k + 1) * 64 + b];
          a1 += wi.z * st[(k0 + k + 2) * 64 + b];
          a2 += wi.w * st[(k0 + k + 3) * 64 + b];
        }
      }
      __syncthreads();
      stage64(h1p, st, tid);
      __syncthreads();
      {
        const float4* wh4 = (const float4*)(wB[q] + 256 + k0);
        #pragma unroll 8
        for (int k = 0; k < 128; k += 4) {
          float4 wh = wh4[k >> 2];
          a1 += wh.x * st[(k0 + k)     * 64 + b];
          a2 += wh.y * st[(k0 + k + 1) * 64 + b];
          a1 += wh.z * st[(k0 + k + 2) * 64 + b];
          a2 += wh.w * st[(k0 + k + 3) * 64 + b];
        }
      }
      red[ks][q][b] = (ks ? 0.f : bs[1][q]) + (a1 + a2);
      __syncthreads();
      if (tid < 64) {
        float gi = red[0][0][tid] + red[1][0][tid];
        float gf = red[0][1][tid] + red[1][1][tid];
        float gg = red[0][2][tid] + red[1][2][tid];
        float go = red[0][3][tid] + red[1][3][tid];
        c1 = sigm(gf) * c1 + sigm(gi) * tanh_f(gg);
        gstore(&h1n[bi * B + tid], sigm(go) * tanh_f(c1));
      }
    }
    gbar(bar, 4 * t + 2);

    // ---------- layer 2 ----------
    {
      stage64(h1n, st, tid);
      __syncthreads();
      const int k0 = ks << 7;
      float a1 = 0.f, a2 = 0.f;
      {
        const float4* wi4 = (const float4*)(wC[q] + k0);
        #pragma unroll 8
        for (int k = 0; k < 128; k += 4) {
          float4 wi = wi4[k >> 2];
          a1 += wi.x * st[(k0 + k)     * 64 + b];
          a2 += wi.y * st[(k0 + k + 1) * 64 + b];
          a1 += wi.z * st[(k0 + k + 2) * 64 + b];
          a2 += wi.w * st[(k0 + k + 3) * 64 + b];
        }
      }
      __syncthreads();
      stage64(h2p, st, tid);
      __syncthreads();
      {
        const float4* wh4 = (const float4*)(wC[q] + 256 + k0);
        #pragma unroll 8
        for (int k = 0; k < 128; k += 4) {
          float4 wh = wh4[k >> 2];
          a1 += wh.x * st[(k0 + k)     * 64 + b];
          a2 += wh.y * st[(k0 + k + 1) * 64 + b];
          a1 += wh.z * st[(k0 + k + 2) * 64 + b];
          a2 += wh.w * st[(k0 + k + 3) * 64 + b];
        }
      }
      red[ks][q][b] = (ks ? 0.f : bs[2][q]) + (a1 + a2);
      __syncthreads();
      if (tid < 64) {
        float gi = red[0][0][tid] + red[1][0][tid];
        float gf = red[0][1][tid] + red[1][1][tid];
        float gg = red[0][2][tid] + red[1][2][tid];
        float go = red[0][3][tid] + red[1][3][tid];
        c2 = sigm(gf) * c2 + sigm(gi) * tanh_f(gg);
        gstore(&h2n[bi * B + tid], sigm(go) * tanh_f(c2));
      }
    }
    gbar(bar, 4 * t + 3);

    // ---------- attention (interleaved rows, unnormalized exp) ----------
    {
      float* ctxn = ctxa + (long)(t + 1) * KVB;
      float q0 = gload(&h2n[(4 * alane + 0) * B + ab]);
      float q1 = gload(&h2n[(4 * alane + 1) * B + ab]);
      float q2 = gload(&h2n[(4 * alane + 2) * B + ab]);
      float q3 = gload(&h2n[(4 * alane + 3) * B + ab]);
      float a0 = 0.f, a1 = 0.f, a2 = 0.f, a3 = 0.f, zp = 0.f;
      for (int r = aseg; r < alen; r += 32) {
        size_t off = ((size_t)(ab * T + r)) * KV + 4 * alane;
        uint2 kd = *(const uint2*)(kbf + off);
        uint2 vd = *(const uint2*)(vbf + off);
        float e = bf2f(kd.x & 0xffffu) * q0
                + __uint_as_float(kd.x & 0xffff0000u) * q1
                + bf2f(kd.y & 0xffffu) * q2
                + __uint_as_float(kd.y & 0xffff0000u) * q3;
        #pragma unroll
        for (int o = 32; o; o >>= 1) e += __shfl_xor(e, o, 64);
        float w = __expf(fminf(e, 50.f));
        a0 += w * bf2f(vd.x & 0xffffu);
        a1 += w * __uint_as_float(vd.x & 0xffff0000u);
        a2 += w * bf2f(vd.y & 0xffffu);
        a3 += w * __uint_as_float(vd.y & 0xffff0000u);
        zp += w;
      }
      int wv = tid >> 6;
      asum[wv][alane] = make_float4(a0, a1, a2, a3);
      if (alane == 0) az[wv] = zp;
      __syncthreads();
      if (tid < 256) {
        const float* as = (const float*)asum;
        float s = as[tid]        + as[256 + tid]  + as[512 + tid]  + as[768 + tid]
                + as[1024 + tid] + as[1280 + tid] + as[1536 + tid] + as[1792 + tid];
        atomicAdd(&ctxn[tid * B + ab], s);
      }
      if (tid == 0) {
        atomicAdd(&za[(t + 1) * B + ab],
                  az[0] + az[1] + az[2] + az[3] + az[4] + az[5] + az[6] + az[7]);
      }
    }
    gbar(bar, 4 * t + 4);
  }
}

// ---------- LSTM cells (legacy fallback) ----------
__global__ __launch_bounds__(512) void k_cell0(
    const float* __restrict__ wih, const float* __restrict__ whh,
    const float* __restrict__ bih, const float* __restrict__ bhh,
    const float* __restrict__ xe,
    const float* __restrict__ ctx, const float* __restrict__ Z,
    const float* __restrict__ hprev,
    float* __restrict__ hnew, float* __restrict__ cst) {
  int t = threadIdx.x;
  int b = t & 63, q = (t >> 6) & 3, ks = t >> 8;
  int j = blockIdx.x;
  int row = q * H + j;
  float acc = 0.f, s0 = 0.f, s1 = 0.f, s2 = 0.f, s3 = 0.f, a2 = 0.f;
  if (ks == 0) {
    acc = bih[row] + bhh[row];
    const float* wi = wih + (long)row * (E + KV);
    #pragma unroll 4
    for (int k = 0; k < E; k += 4) {
      s0 += wi[k]   * xe[(k)   * B + b];
      s1 += wi[k+1] * xe[(k+1) * B + b];
      s2 += wi[k+2] * xe[(k+2) * B + b];
      s3 += wi[k+3] * xe[(k+3) * B + b];
    }
    const float* wh = whh + (long)row * H;
    #pragma unroll 4
    for (int k = 0; k < 128; k += 2) {
      a2 += wh[k]   * hprev[(k)   * B + b];
      a2 += wh[k+1] * hprev[(k+1) * B + b];
    }
    acc += (s0 + s1) + (s2 + s3) + a2;
  } else {
    float zz = 1.f / fmaxf(Z[b], 1e-12f);
    const float* wi = wih + (long)row * (E + KV) + E;
    #pragma unroll 4
    for (int k = 0; k < KV; k += 4) {
      s0 += wi[k]   * ctx[(k)   * B + b];
      s1 += wi[k+1] * ctx[(k+1) * B + b];
      s2 += wi[k+2] * ctx[(k+2) * B + b];
      s3 += wi[k+3] * ctx[(k+3) * B + b];
    }
    const float* wh = whh + (long)row * H + 128;
    #pragma unroll 4
    for (int k = 0; k < 128; k += 2) {
      a2 += wh[k]   * hprev[(128 + k)     * B + b];
      a2 += wh[k+1] * hprev[(128 + k + 1) * B + b];
    }
    acc = ((s0 + s1) + (s2 + s3)) * zz + a2;
  }
  __shared__ float sh[2][4][64];
  sh[ks][q][b] = acc;
  __syncthreads();
  if (t < 64) {
    int bb = t;
    float gi = sh[0][0][bb] + sh[1][0][bb];
    float gf = sh[0][1][bb] + sh[1][1][bb];
    float gg = sh[0][2][bb] + sh[1][2][bb];
    float go = sh[0][3][bb] + sh[1][3][bb];
    float c = sigm(gf) * cst[j * B + bb] + sigm(gi) * tanh_f(gg);
    float h = sigm(go) * tanh_f(c);
    cst[j * B + bb] = c;
    hnew[j * B + bb] = h;
  }
}

__global__ __launch_bounds__(512) void k_cellr(
    const float* __restrict__ wih, const float* __restrict__ whh,
    const float* __restrict__ bih, const float* __restrict__ bhh,
    const float* __restrict__ hin, const float* __restrict__ hprevL,
    float* __restrict__ hnewL, float* __restrict__ cst,
    float* __restrict__ ctxn, float* __restrict__ Zn, float* __restrict__ m, int aux) {
  int t = threadIdx.x;
  int b = t & 63, q = (t >> 6) & 3, ks = t >> 8;
  int j = blockIdx.x;
  int row = q * H + j;
  if (aux) {
    int gid = blockIdx.x * 512 + t;
    if (gid < KV * B) ctxn[gid] = 0.f;
    if (gid < B) { Zn[gid] = 0.f; m[gid] = -3.4e38f; }
  }
  float acc = ks ? 0.f : (bih[row] + bhh[row]);
  float a1 = 0.f, a2 = 0.f, a3 = 0.f, a4 = 0.f;
  const float* wi = wih + (long)row * H + ks * 128;
  const float* wh = whh + (long)row * H + ks * 128;
  int k0 = ks * 128;
  #pragma unroll 4
  for (int k = 0; k < 128; k += 2) {
    a1 += wi[k]   * hin[(k0 + k)     * B + b];
    a2 += wi[k+1] * hin[(k0 + k + 1) * B + b];
    a3 += wh[k]   * hprevL[(k0 + k)     * B + b];
    a4 += wh[k+1] * hprevL[(k0 + k + 1) * B + b];
  }
  acc += (a1 + a2) + (a3 + a4);
  __shared__ float sh[2][4][64];
  sh[ks][q][b] = acc;
  __syncthreads();
  if (t < 64) {
    int bb = t;
    float gi = sh[0][0][bb] + sh[1][0][bb];
    float gf = sh[0][1][bb] + sh[1][1][bb];
    float gg = sh[0][2][bb] + sh[1][2][bb];
    float go = sh[0][3][bb] + sh[1][3][bb];
    float c = sigm(gf) * cst[j * B + bb] + sigm(gi) * tanh_f(gg);
    float h = sigm(go) * tanh_f(c);
    cst[j * B + bb] = c;
    hnewL[j * B + bb] = h;
  }
}

// ---------- deferred MLP head (new path) ----------
__global__ __launch_bounds__(256) void k_fc1c(
    const float* __restrict__ w, const float* __restrict__ bias,
    const float* __restrict__ h2a, const float* __restrict__ ctxa,
    const float* __restrict__ za, float* __restrict__ hidc, int t0) {
  int s = blockIdx.y;
  int t = t0 + s;
  const float* h2  = h2a  + (long)(t + 1) * HB;
  const float* ctx = ctxa + (long)(t + 1) * KVB;
  int tid = threadIdx.x;
  int b = tid & 63, jl = tid >> 6;
  int j = blockIdx.x * 4 + jl;
  float zz = 1.f / fmaxf(za[(t + 1) * B + b], 1e-12f);
  const float* wr = w + (long)j * (H + KV);
  float s0 = 0.f, s1 = 0.f, c0 = 0.f, c1 = 0.f;
  #pragma unroll 4
  for (int k = 0; k < 256; k += 2) {
    s0 += wr[k]       * h2[(k)   * B + b];
    s1 += wr[k+1]     * h2[(k+1) * B + b];
    c0 += wr[256 + k]   * ctx[(k)   * B + b];
    c1 += wr[256 + k+1] * ctx[(k+1) * B + b];
  }
  float acc = bias[j] + (s0 + s1) + (c0 + c1) * zz;
  hidc[((long)s * MH + j) * B + b] = fmaxf(acc, 0.f);
}

__global__ __launch_bounds__(64) void k_fc2c(
    const float* __restrict__ w, const float* __restrict__ bias,
    const float* __restrict__ hidc, float* __restrict__ out, int t0) {
  int s = blockIdx.y;
  int v = blockIdx.x;
  int b = threadIdx.x;
  const float* hid = hidc + (long)s * MH * B;
  const float* wr = w + (long)v * MH;
  float s0 = 0.f, s1 = 0.f, s2 = 0.f, s3 = 0.f;
  #pragma unroll 4
  for (int k = 0; k < MH; k += 4) {
    s0 += wr[k]   * hid[(k)   * B + b];
    s1 += wr[k+1] * hid[(k+1) * B + b];
    s2 += wr[k+2] * hid[(k+2) * B + b];
    s3 += wr[k+3] * hid[(k+3) * B + b];
  }
  out[((long)b * L + (t0 + s)) * V + v] = bias[v] + (s0 + s1) + (s2 + s3);
}

// ---------- legacy fallback extras ----------
template <int BF>
__global__ __launch_bounds__(256) void k_energy(
    const void* __restrict__ keyp, const float* __restrict__ h2,
    const int* __restrict__ lens, float* __restrict__ e, float* __restrict__ m) {
  int b = blockIdx.y;
  int len = lens[b];
  int wave = threadIdx.x >> 6, lane = threadIdx.x & 63;
  int t0 = (blockIdx.x * 4 + wave) * 16;
  if (t0 >= len) return;
  float h0 = h2[(4 * lane + 0) * B + b];
  float h1 = h2[(4 * lane + 1) * B + b];
  float h2v = h2[(4 * lane + 2) * B + b];
  float h3 = h2[(4 * lane + 3) * B + b];
  int tend = min(t0 + 16, len);
  float wmax = -3.4e38f;
  for (int t = t0; t < tend; t++) {
    float4 kv;
    if (BF) {
      const uint2* p = (const uint2*)((const ushort*)keyp + (size_t)(b * T + t) * KV + 4 * lane);
      uint2 d = *p;
      kv.x = bf2f(d.x & 0xffffu);
      kv.y = __uint_as_float(d.x & 0xffff0000u);
      kv.z = bf2f(d.y & 0xffffu);
      kv.w = __uint_as_float(d.y & 0xffff0000u);
    } else {
      kv = ((const float4*)((const float*)keyp + (size_t)(b * T + t) * KV))[lane];
    }
    float s = kv.x * h0 + kv.y * h1 + kv.z * h2v + kv.w * h3;
    #pragma unroll
    for (int off = 32; off; off >>= 1) s += __shfl_xor(s, off, 64);
    if (lane == 0) e[b * T + t] = s;
    wmax = fmaxf(wmax, s);
  }
  if (lane == 0) atomicMaxFloat(&m[b], wmax);
}

template <int BF>
__global__ __launch_bounds__(256) void k_pv(
    const void* __restrict__ valp, const float* __restrict__ e, const float* __restrict__ m,
    const int* __restrict__ lens, float* __restrict__ ctxn, float* __restrict__ Zn) {
  int b = blockIdx.y;
  int len = lens[b];
  int t0blk = blockIdx.x * 256;
  if (t0blk >= len) return;
  int wave = threadIdx.x >> 6, lane = threadIdx.x & 63;
  float mb = m[b];
  float a0 = 0.f, a1 = 0.f, a2 = 0.f, a3 = 0.f, zp = 0.f;
  int t0 = t0blk + wave * 64;
  int tend = min(t0 + 64, len);
  for (int t = t0; t < tend; t++) {
    float w = __expf(e[b * T + t] - mb);
    float4 vv;
    if (BF) {
      const uint2* p = (const uint2*)((const ushort*)valp + (size_t)(b * T + t) * KV + 4 * lane);
      uint2 d = *p;
      vv.x = bf2f(d.x & 0xffffu);
      vv.y = __uint_as_float(d.x & 0xffff0000u);
      vv.z = bf2f(d.y & 0xffffu);
      vv.w = __uint_as_float(d.y & 0xffff0000u);
    } else {
      vv = ((const float4*)((const float*)valp + (size_t)(b * T + t) * KV))[lane];
    }
    a0 += w * vv.x; a1 += w * vv.y; a2 += w * vv.z; a3 += w * vv.w;
    zp += w;
  }
  __shared__ float sh[4][256];
  __shared__ float shz[4];
  sh[wave][4 * lane + 0] = a0;
  sh[wave][4 * lane + 1] = a1;
  sh[wave][4 * lane + 2] = a2;
  sh[wave][4 * lane + 3] = a3;
  if (lane == 0) shz[wave] = zp;
  __syncthreads();
  if (wave == 0) {
    #pragma unroll
    for (int r = 0; r < 4; r++) {
      int d = lane * 4 + r;
      float s = sh[0][d] + sh[1][d] + sh[2][d] + sh[3][d];
      atomicAdd(&ctxn[d * B + b], s);
    }
    if (lane == 0) atomicAdd(&Zn[b], shz[0] + shz[1] + shz[2] + shz[3]);
  }
}

__global__ __launch_bounds__(256) void k_fc1(
    const float* __restrict__ w, const float* __restrict__ bias,
    const float* __restrict__ h2, const float* __restrict__ ctxn, const float* __restrict__ Zn,
    float* __restrict__ hid) {
  int t = threadIdx.x;
  int b = t & 63, jl = t >> 6;
  int j = blockIdx.x * 4 + jl;
  float zz = 1.f / fmaxf(Zn[b], 1e-12f);
  const float* wr = w + (long)j * (H + KV);
  float s0 = 0.f, s1 = 0.f, s2 = 0.f, s3 = 0.f, a2 = 0.f, a3 = 0.f;
  #pragma unroll 4
  for (int k = 0; k < H; k += 4) {
    s0 += wr[k]   * h2[(k)   * B + b];
    s1 += wr[k+1] * h2[(k+1) * B + b];
    s2 += wr[k+2] * h2[(k+2) * B + b];
    s3 += wr[k+3] * h2[(k+3) * B + b];
  }
  #pragma unroll 4
  for (int k = 0; k < KV; k += 2) {
    a2 += wr[H + k]     * ctxn[(k)   * B + b];
    a3 += wr[H + k + 1] * ctxn[(k+1) * B + b];
  }
  float acc = bias[j] + (s0 + s1) + (s2 + s3) + (a2 + a3) * zz;
  hid[j * B + b] = fmaxf(acc, 0.f);
}

__global__ __launch_bounds__(64) void k_fc2(
    const float* __restrict__ w, const float* __restrict__ bias,
    const float* __restrict__ hid, float* __restrict__ out, int step) {
  int b = threadIdx.x;
  int v = blockIdx.x;
  const float* wr = w + (long)v * MH;
  float s0 = 0.f, s1 = 0.f, s2 = 0.f, s3 = 0.f;
  #pragma unroll 4
  for (int k = 0; k < MH; k += 4) {
    s0 += wr[k]   * hid[(k)   * B + b];
    s1 += wr[k+1] * hid[(k+1) * B + b];
    s2 += wr[k+2] * hid[(k+2) * B + b];
    s3 += wr[k+3] * hid[(k+3) * B + b];
  }
  out[((long)b * L + step) * V + v] = bias[v] + (s0 + s1) + (s2 + s3);
}

static void launch_legacy(const float* key, const float* value, const int* lens,
                          const float* w_ih0, const float* w_hh0,
                          const float* b_ih0, const float* b_hh0,
                          const float* w_ihr, const float* w_hhr,
                          const float* b_ihr, const float* b_hhr,
                          const float* fc1_w, const float* fc1_b,
                          const float* fc2_w, const float* fc2_b,
                          float* out, float* ws,
                          const ushort* kbf, const ushort* vbf, bool bf,
                          hipStream_t stream) {
  float* hbuf = ws + OFF_H;
  float* cbuf = ws + OFF_C;
  float* ctxb = ws + OFF_CTX;
  float* Zb   = ws + OFF_Z;
  float* mb   = ws + OFF_M;
  float* eb   = ws + OFF_E;
  float* hid  = ws + OFF_HID;
  float* xe   = ws + OFF_XE;
  for (int t = 0; t < L; t++) {
    int cur = t & 1, nxt = cur ^ 1;
    float* hprev = hbuf + (long)cur * 3 * HB;
    float* hnew  = hbuf + (long)nxt * 3 * HB;
    float* ctxc  = ctxb + (long)cur * KV * B;
    float* ctxn  = ctxb + (long)nxt * KV * B;
    float* Zc = Zb + cur * B;
    float* Zn = Zb + nxt * B;

    k_cell0<<<H, 512, 0, stream>>>(w_ih0, w_hh0, b_ih0, b_hh0,
                                   xe + (long)t * E * B, ctxc, Zc,
                                   hprev, hnew, cbuf);
    k_cellr<<<H, 512, 0, stream>>>(w_ihr, w_hhr, b_ihr, b_hhr,
                                   hnew, hprev + HB, hnew + HB, cbuf + HB,
                                   ctxn, Zn, mb, 1);
    k_cellr<<<H, 512, 0, stream>>>(w_ihr + (long)G * H, w_hhr + (long)G * H,
                                   b_ihr + G, b_hhr + G,
                                   hnew + HB, hprev + 2 * HB, hnew + 2 * HB, cbuf + 2 * HB,
                                   nullptr, nullptr, nullptr, 0);
    if (bf) {
      k_energy<1><<<dim3(T / 64, B), 256, 0, stream>>>(kbf, hnew + 2 * HB, lens, eb, mb);
      k_pv<1><<<dim3(T / 256, B), 256, 0, stream>>>(vbf, eb, mb, lens, ctxn, Zn);
    } else {
      k_energy<0><<<dim3(T / 64, B), 256, 0, stream>>>(key, hnew + 2 * HB, lens, eb, mb);
      k_pv<0><<<dim3(T / 256, B), 256, 0, stream>>>(value, eb, mb, lens, ctxn, Zn);
    }
    k_fc1<<<MH / 4, 256, 0, stream>>>(fc1_w, fc1_b, hnew + 2 * HB, ctxn, Zn, hid);
    k_fc2<<<V, 64, 0, stream>>>(fc2_w, fc2_b, hid, out, t);
  }
}

extern "C" void kernel_launch(void* const* d_in, const int* in_sizes, int n_in,
                              void* d_out, int out_size, void* d_ws, size_t ws_size,
                              hipStream_t stream) {
  const float* key    = (const float*)d_in[0];
  const float* value  = (const float*)d_in[1];
  const int*   labels = (const int*)d_in[2];
  const int*   lens   = (const int*)d_in[3];
  const float* emb    = (const float*)d_in[4];
  const float* w_ih0  = (const float*)d_in[5];
  const float* w_hh0  = (const float*)d_in[6];
  const float* b_ih0  = (const float*)d_in[7];
  const float* b_hh0  = (const float*)d_in[8];
  const float* w_ihr  = (const float*)d_in[9];
  const float* w_hhr  = (const float*)d_in[10];
  const float* b_ihr  = (const float*)d_in[11];
  const float* b_hhr  = (const float*)d_in[12];
  const float* fc1_w  = (const float*)d_in[13];
  const float* fc1_b  = (const float*)d_in[14];
  const float* fc2_w  = (const float*)d_in[15];
  const float* fc2_b  = (const float*)d_in[16];
  float* out = (float*)d_out;
  float* ws  = (float*)d_ws;

  bool bf      = ((long)ws_size >= NEED_BF);
  bool newpath = ((long)ws_size >= NEED_NEW);
  ushort* kbf = (ushort*)((char*)d_ws + FLOATBYTES);
  ushort* vbf = kbf + KVELEMS;

  k_embed<<<(L * E * B + 255) / 256, 256, 0, stream>>>(labels, emb, ws + OFF_XE);
  if (bf) {
    int n4 = (int)(KVELEMS >> 2);
    k_cvt<<<4096, 256, 0, stream>>>((const float4*)key, (ushort4*)kbf, n4);
    k_cvt<<<4096, 256, 0, stream>>>((const float4*)value, (ushort4*)vbf, n4);
  }

  if (newpath) {
    k_init2<<<(int)(((long)(L + 1) * KVB + 255) / 256), 256, 0, stream>>>(ws);
    float* h01  = ws + NOFF_H01;
    float* h2a  = ws + NOFF_H2;
    float* ctxa = ws + NOFF_CTXA;
    float* za   = ws + NOFF_ZA;
    float* hidc = ws + NOFF_HIDC;
    float* xep  = ws + OFF_XE;
    unsigned* bar = (unsigned*)(ws + OFF_H);

    k_mega<<<256, 512, 0, stream>>>(w_ih0, w_hh0, b_ih0, b_hh0,
                                    w_ihr, w_hhr, b_ihr, b_hhr,
                                    kbf, vbf, lens, xep,
                                    h01, h2a, ctxa, za, bar);

    for (int c = 0; c < L / CS; c++) {
      int t0 = c * CS;
      k_fc1c<<<dim3(MH / 4, CS), 256, 0, stream>>>(fc1_w, fc1_b, h2a, ctxa, za, hidc, t0);
      k_fc2c<<<dim3(V, CS), 64, 0, stream>>>(fc2_w, fc2_b, hidc, out, t0);
    }
  } else {
    k_init<<<(3 * HB + 255) / 256, 256, 0, stream>>>(ws);
    launch_legacy(key, value, lens, w_ih0, w_hh0, b_ih0, b_hh0,
                  w_ihr, w_hhr, b_ihr, b_hhr, fc1_w, fc1_b, fc2_w, fc2_b,
                  out, ws, kbf, vbf, bf, stream);
  }
}